// Round 2
// baseline (2230.967 us; speedup 1.0000x reference)
//
#include <hip/hip_runtime.h>
#include <cstddef>

// Problem constants
#define B_SZ     2
#define L_SEQ    8192
#define D_INNERC 1024
#define NHEADSC  16
#define CHUNKC   64
#define NCHUNKC  128          // L_SEQ / CHUNK
#define CONV_DIMC 1280
#define D_PROJC  2320
#define M_ROWS   16384        // B_SZ * L_SEQ

typedef unsigned short bfu;   // raw bf16 bits

__device__ __forceinline__ float silu_(float v) { return v / (1.f + expf(-v)); }

__device__ __forceinline__ float b2f(bfu u) {
  return __uint_as_float((unsigned)u << 16);
}
__device__ __forceinline__ bfu f2b(float f) {
  unsigned x = __float_as_uint(f);
  return (bfu)((x + 0x7fffu + ((x >> 16) & 1u)) >> 16);   // RNE
}

// --- generic 4-wide load/store (fp32 or bf16 storage, fp32 values) ---------
__device__ __forceinline__ float4 ld4(const float* p) { return *(const float4*)p; }
__device__ __forceinline__ float4 ld4(const bfu* p) {
  ushort4 u = *(const ushort4*)p;
  float4 f;
  f.x = b2f(u.x); f.y = b2f(u.y); f.z = b2f(u.z); f.w = b2f(u.w);
  return f;
}
__device__ __forceinline__ void st4(float* p, float4 v) { *(float4*)p = v; }
__device__ __forceinline__ void st4(bfu* p, float4 v) {
  ushort4 u;
  u.x = f2b(v.x); u.y = f2b(v.y); u.z = f2b(v.z); u.w = f2b(v.w);
  *(ushort4*)p = u;
}
__device__ __forceinline__ float ld1(const float* p) { return *p; }
__device__ __forceinline__ float ld1(const bfu* p) { return b2f(*p); }
__device__ __forceinline__ void st1(float* p, float v) { *p = v; }
__device__ __forceinline__ void st1(bfu* p, float v) { *p = f2b(v); }

// pos in original time order for (b, chunk c, local l) of direction dir
__device__ __forceinline__ int pos_of(int b, int c, int l, int dir) {
  int t = c * CHUNKC + l;
  return dir ? (b * L_SEQ + (L_SEQ - 1) - t) : (b * L_SEQ + t);
}

// ---------------------------------------------------------------------------
// GEMM (NT): C[m][n] (+)= sum_k A[m][k] * Bw[n][k]   (both K-contiguous)
// 128x128 tile, BK=16, 256 threads, 8x8 microtile. M % 128 == 0, K % 16 == 0.
// accum: 1 -> C += acc (TC=float only); bias added when accum==0 && bias.
// ---------------------------------------------------------------------------
template <typename TA, typename TB, typename TC>
__global__ __launch_bounds__(256)
void gemm_nt(const TA* __restrict__ A, int lda,
             const TB* __restrict__ Bw, int ldb,
             TC* __restrict__ C, int ldc,
             int M, int N, int K,
             const float* __restrict__ bias, int accum)
{
  __shared__ float As[16][132];   // [k][m], padded
  __shared__ float Bs[16][132];   // [k][n]
  const int tid = threadIdx.x;
  const int n0 = blockIdx.x * 128;
  const int m0 = blockIdx.y * 128;
  const int tx = tid & 15, ty = tid >> 4;
  float acc[8][8] = {};

  for (int k0 = 0; k0 < K; k0 += 16) {
#pragma unroll
    for (int r = 0; r < 2; ++r) {
      int q = tid + r * 256;            // 0..511 4-elem slots
      int row = q >> 2, cc = (q & 3) << 2;
      float4 va = ld4(A + (size_t)(m0 + row) * lda + k0 + cc);
      As[cc + 0][row] = va.x; As[cc + 1][row] = va.y;
      As[cc + 2][row] = va.z; As[cc + 3][row] = va.w;
      float4 vb = {0.f, 0.f, 0.f, 0.f};
      if (n0 + row < N)
        vb = ld4(Bw + (size_t)(n0 + row) * ldb + k0 + cc);
      Bs[cc + 0][row] = vb.x; Bs[cc + 1][row] = vb.y;
      Bs[cc + 2][row] = vb.z; Bs[cc + 3][row] = vb.w;
    }
    __syncthreads();
#pragma unroll
    for (int kk = 0; kk < 16; ++kk) {
      float a[8], b[8];
      *(float4*)(a)     = *(float4*)&As[kk][ty * 8];
      *(float4*)(a + 4) = *(float4*)&As[kk][ty * 8 + 4];
      *(float4*)(b)     = *(float4*)&Bs[kk][tx * 8];
      *(float4*)(b + 4) = *(float4*)&Bs[kk][tx * 8 + 4];
#pragma unroll
      for (int i = 0; i < 8; ++i)
#pragma unroll
        for (int j = 0; j < 8; ++j)
          acc[i][j] += a[i] * b[j];
    }
    __syncthreads();
  }

  const bool full = (n0 + 128 <= N);
#pragma unroll
  for (int i = 0; i < 8; ++i) {
    int m = m0 + ty * 8 + i;
    TC* crow = C + (size_t)m * ldc;
    int n = n0 + tx * 8;
    if (full) {
      float4 v0, v1;
      v0.x = acc[i][0]; v0.y = acc[i][1]; v0.z = acc[i][2]; v0.w = acc[i][3];
      v1.x = acc[i][4]; v1.y = acc[i][5]; v1.z = acc[i][6]; v1.w = acc[i][7];
      if (accum) {
        float4 o0 = ld4(crow + n), o1 = ld4(crow + n + 4);
        v0.x += o0.x; v0.y += o0.y; v0.z += o0.z; v0.w += o0.w;
        v1.x += o1.x; v1.y += o1.y; v1.z += o1.z; v1.w += o1.w;
      } else if (bias) {
        v0.x += bias[n + 0]; v0.y += bias[n + 1]; v0.z += bias[n + 2]; v0.w += bias[n + 3];
        v1.x += bias[n + 4]; v1.y += bias[n + 5]; v1.z += bias[n + 6]; v1.w += bias[n + 7];
      }
      st4(crow + n, v0);
      st4(crow + n + 4, v1);
    } else {
#pragma unroll
      for (int j = 0; j < 8; ++j) {
        int nn = n + j;
        if (nn < N) {
          float v = acc[i][j];
          if (accum) v += ld1(crow + nn);
          else if (bias) v += bias[nn];
          st1(crow + nn, v);
        }
      }
    }
  }
}

// ---------------------------------------------------------------------------
// Transpose ssm_out_w (512 x 1024) -> ssmT (1024 x 512)
// ---------------------------------------------------------------------------
__global__ __launch_bounds__(256)
void transpose_k(const float* __restrict__ in, float* __restrict__ out)
{
  int idx = blockIdx.x * 256 + threadIdx.x;   // 0 .. 524287
  int j = idx >> 9, k = idx & 511;
  out[idx] = in[k * 1024 + j];
}

// ---------------------------------------------------------------------------
// Depthwise causal (dir=0) / anti-causal (dir=1) conv over the xBC slice of
// zx (bf16), + bias, + SiLU -> xBC (bf16, original time order).
// ---------------------------------------------------------------------------
__global__ __launch_bounds__(256)
void conv_k(const bfu* __restrict__ zx, const float* __restrict__ conv_w,
            const float* __restrict__ conv_b, bfu* __restrict__ xBC, int dir)
{
  int ch = blockIdx.x * 256 + threadIdx.x;   // 0..1279
  int m  = blockIdx.y;                       // 0..16383
  int t  = m & (L_SEQ - 1), b = m >> 13;
  float w0 = conv_w[ch * 4 + 0], w1 = conv_w[ch * 4 + 1];
  float w2 = conv_w[ch * 4 + 2], w3 = conv_w[ch * 4 + 3];
  float acc = conv_b[ch];
  const bfu* src = zx + 1024 + ch;
#pragma unroll
  for (int k = 0; k < 4; ++k) {
    int tt = dir ? (t + 3 - k) : (t - 3 + k);
    float w = (k == 0) ? w0 : (k == 1) ? w1 : (k == 2) ? w2 : w3;
    if (tt >= 0 && tt < L_SEQ)
      acc += w * b2f(src[(size_t)(b * L_SEQ + tt) * D_PROJC]);
  }
  xBC[(size_t)m * CONV_DIMC + ch] = f2b(silu_(acc));
}

// ---------------------------------------------------------------------------
// Per (b, chunk, head): dt/softplus, within-chunk cumsum of A*dt,
// chunk states[p][n] = sum_l B[l][n] * exp(acum[63]-acum[l]) * dt[l] * xh[l][p]
// ---------------------------------------------------------------------------
__global__ __launch_bounds__(256)
void states_k(const bfu* __restrict__ zx, const bfu* __restrict__ xBC,
              const float* __restrict__ dt_bias, const float* __restrict__ A_log,
              float* __restrict__ acum_g, float* __restrict__ dt_g,
              bfu* __restrict__ states, int dir)
{
  __shared__ float xs[64 * 64];     // x * dt * decay, [l][p]
  __shared__ float Bsh[64 * 128];   // [l][n]
  __shared__ float s_scale[64];
  int bid = blockIdx.x;
  int h = bid & 15, c = (bid >> 4) & 127, b = bid >> 11;
  int tid = threadIdx.x;

  if (tid < 64) {
    int l = tid;
    int pos = pos_of(b, c, l, dir);
    float dtr = b2f(zx[(size_t)pos * D_PROJC + 2304 + h]) + dt_bias[h];
    float dt = (dtr > 20.f) ? dtr : log1pf(expf(dtr));
    float a = -expf(A_log[h]) * dt;
#pragma unroll
    for (int off = 1; off < 64; off <<= 1) {
      float v = __shfl_up(a, off);
      if (l >= off) a += v;
    }
    float alast = __shfl(a, 63);
    s_scale[l] = dt * expf(alast - a);
    int gi = ((b * NCHUNKC + c) * NHEADSC + h) * 64 + l;
    acum_g[gi] = a; dt_g[gi] = dt;
  }
  __syncthreads();

#pragma unroll
  for (int r = 0; r < 4; ++r) {
    int q = tid + r * 256;          // 0..1023
    int row = q >> 4, cc = (q & 15) << 2;
    int pos = pos_of(b, c, row, dir);
    float4 v = ld4(xBC + (size_t)pos * CONV_DIMC + h * 64 + cc);
    float sc = s_scale[row];
    v.x *= sc; v.y *= sc; v.z *= sc; v.w *= sc;
    *(float4*)&xs[row * 64 + cc] = v;
  }
#pragma unroll
  for (int r = 0; r < 8; ++r) {
    int q = tid + r * 256;          // 0..2047
    int row = q >> 5, cc = (q & 31) << 2;
    int pos = pos_of(b, c, row, dir);
    *(float4*)&Bsh[row * 128 + cc] = ld4(xBC + (size_t)pos * CONV_DIMC + 1024 + cc);
  }
  __syncthreads();

  int tn = tid & 15, tp = tid >> 4;   // p micro 4, n micro 8
  float acc[4][8] = {};
  for (int l = 0; l < 64; ++l) {
    float a4[4], b8[8];
    *(float4*)a4       = *(float4*)&xs[l * 64 + tp * 4];
    *(float4*)(b8)     = *(float4*)&Bsh[l * 128 + tn * 8];
    *(float4*)(b8 + 4) = *(float4*)&Bsh[l * 128 + tn * 8 + 4];
#pragma unroll
    for (int i = 0; i < 4; ++i)
#pragma unroll
      for (int j = 0; j < 8; ++j)
        acc[i][j] += a4[i] * b8[j];
  }
  size_t base = ((size_t)(b * NCHUNKC + c) * NHEADSC + h) * 8192;
#pragma unroll
  for (int i = 0; i < 4; ++i) {
    int p = tp * 4 + i;
    float4 v0, v1;
    v0.x = acc[i][0]; v0.y = acc[i][1]; v0.z = acc[i][2]; v0.w = acc[i][3];
    v1.x = acc[i][4]; v1.y = acc[i][5]; v1.z = acc[i][6]; v1.w = acc[i][7];
    st4(states + base + p * 128 + tn * 8, v0);
    st4(states + base + p * 128 + tn * 8 + 4, v1);
  }
}

// ---------------------------------------------------------------------------
// Inter-chunk scan: states[c] <- prefix state entering chunk c (in place).
// prefix in fp32 registers across all 128 chunks. 256 blocks: (b,h,eb)
// ---------------------------------------------------------------------------
__global__ __launch_bounds__(256)
void scan_k(bfu* __restrict__ states, const float* __restrict__ acum_g)
{
  int bid = blockIdx.x;
  int eb = bid & 7, h = (bid >> 3) & 15, b = bid >> 7;
  int e = eb * 1024 + threadIdx.x * 4;
  float4 pre = {0.f, 0.f, 0.f, 0.f};
  for (int c = 0; c < NCHUNKC; ++c) {
    size_t base = ((size_t)(b * NCHUNKC + c) * NHEADSC + h) * 8192;
    float d = expf(acum_g[((b * NCHUNKC + c) * NHEADSC + h) * 64 + 63]);
    float4 v = ld4(states + base + e);
    st4(states + base + e, pre);
    pre.x = v.x + d * pre.x; pre.y = v.y + d * pre.y;
    pre.z = v.z + d * pre.z; pre.w = v.w + d * pre.w;
  }
}

// ---------------------------------------------------------------------------
// Per (b, chunk, head): Y = (L o C B^T) * dt @ xh + exp(acum) * (C @ prefix^T)
//                          + D_skip * xh     -> ybuf (original time order)
// ---------------------------------------------------------------------------
__global__ __launch_bounds__(256)
void y_k(const bfu* __restrict__ xBC, const bfu* __restrict__ states,
         const float* __restrict__ acum_g, const float* __restrict__ dt_g,
         const float* __restrict__ D_skip, bfu* __restrict__ ybuf, int dir)
{
  __shared__ float smem[11008];
  __shared__ float s_acum[64], s_dt[64];
  float* Cs  = smem;              // 64 x 36  [l][nn]
  float* Bs2 = smem + 2304;       // 64 x 36  [s][nn]
  float* Ps  = smem + 4608;       // 64 x 36  [p][nn]
  float* xh  = smem + 6912;       // 64 x 64  [s][p]
  float* sc  = smem;              // 64 x 68  [l][s]  (overlays Cs+Bs2 after use)

  int bid = blockIdx.x;
  int h = bid & 15, c = (bid >> 4) & 127, b = bid >> 11;
  int tid = threadIdx.x;
  if (tid < 64) {
    int gi = ((b * NCHUNKC + c) * NHEADSC + h) * 64 + tid;
    s_acum[tid] = acum_g[gi]; s_dt[tid] = dt_g[gi];
  }
#pragma unroll
  for (int r = 0; r < 4; ++r) {
    int q = tid + r * 256;
    int row = q >> 4, cc = (q & 15) << 2;
    int pos = pos_of(b, c, row, dir);
    *(float4*)&xh[row * 64 + cc] = ld4(xBC + (size_t)pos * CONV_DIMC + h * 64 + cc);
  }

  int ts = tid & 15, tl = tid >> 4;
  float sacc[4][4] = {}, yacc[4][4] = {};
  size_t pbase = ((size_t)(b * NCHUNKC + c) * NHEADSC + h) * 8192;

  for (int nc = 0; nc < 4; ++nc) {
    __syncthreads();
#pragma unroll
    for (int r = 0; r < 2; ++r) {
      int q = tid + r * 256;            // 0..511
      int row = q >> 3, cc = (q & 7) << 2;
      int pos = pos_of(b, c, row, dir);
      *(float4*)&Cs[row * 36 + cc]  = ld4(xBC + (size_t)pos * CONV_DIMC + 1152 + nc * 32 + cc);
      *(float4*)&Bs2[row * 36 + cc] = ld4(xBC + (size_t)pos * CONV_DIMC + 1024 + nc * 32 + cc);
      *(float4*)&Ps[row * 36 + cc]  = ld4(states + pbase + row * 128 + nc * 32 + cc);
    }
    __syncthreads();
#pragma unroll
    for (int nn = 0; nn < 32; nn += 4) {
      float cf[4][4], bf[4][4], pf[4][4];
#pragma unroll
      for (int i = 0; i < 4; ++i)
        *(float4*)cf[i] = *(float4*)&Cs[(tl * 4 + i) * 36 + nn];
#pragma unroll
      for (int j = 0; j < 4; ++j) {
        *(float4*)bf[j] = *(float4*)&Bs2[(ts * 4 + j) * 36 + nn];
        *(float4*)pf[j] = *(float4*)&Ps[(ts * 4 + j) * 36 + nn];
      }
#pragma unroll
      for (int i = 0; i < 4; ++i)
#pragma unroll
        for (int j = 0; j < 4; ++j)
#pragma unroll
          for (int k = 0; k < 4; ++k) {
            sacc[i][j] += cf[i][k] * bf[j][k];
            yacc[i][j] += cf[i][k] * pf[j][k];
          }
    }
  }
  __syncthreads();
#pragma unroll
  for (int i = 0; i < 4; ++i)
#pragma unroll
    for (int j = 0; j < 4; ++j) {
      int l = tl * 4 + i, s = ts * 4 + j;
      float v = 0.f;
      if (s <= l) v = sacc[i][j] * expf(s_acum[l] - s_acum[s]) * s_dt[s];
      sc[l * 68 + s] = v;
    }
  __syncthreads();

  float Dh = D_skip[h];
  float yout[4][4];
#pragma unroll
  for (int i = 0; i < 4; ++i) {
    int l = tl * 4 + i;
    float dec = expf(s_acum[l]);
#pragma unroll
    for (int j = 0; j < 4; ++j) {
      int p = ts * 4 + j;
      yout[i][j] = yacc[i][j] * dec + Dh * xh[l * 64 + p];
    }
  }
#pragma unroll
  for (int s4 = 0; s4 < 64; s4 += 4) {
    float sf[4][4], xf[4][4];
#pragma unroll
    for (int i = 0; i < 4; ++i)
      *(float4*)sf[i] = *(float4*)&sc[(tl * 4 + i) * 68 + s4];
#pragma unroll
    for (int k = 0; k < 4; ++k)
      *(float4*)xf[k] = *(float4*)&xh[(s4 + k) * 64 + ts * 4];
#pragma unroll
    for (int i = 0; i < 4; ++i)
#pragma unroll
      for (int j = 0; j < 4; ++j)
#pragma unroll
        for (int k = 0; k < 4; ++k)
          yout[i][j] += sf[i][k] * xf[k][j];
  }
#pragma unroll
  for (int i = 0; i < 4; ++i) {
    int l = tl * 4 + i;
    int pos = pos_of(b, c, l, dir);
    float4 v; v.x = yout[i][0]; v.y = yout[i][1]; v.z = yout[i][2]; v.w = yout[i][3];
    st4(ybuf + (size_t)pos * D_INNERC + h * 64 + ts * 4, v);
  }
}

// ---------------------------------------------------------------------------
// Gating (y *= silu(z)) + RMSNorm over 1024 + norm_w, in place on ybuf (bf16)
// ---------------------------------------------------------------------------
__global__ __launch_bounds__(256)
void norm_k(bfu* __restrict__ ybuf, const bfu* __restrict__ zx,
            const float* __restrict__ norm_w)
{
  int m = blockIdx.x, tid = threadIdx.x;
  float4 y = ld4(ybuf + (size_t)m * D_INNERC + tid * 4);
  float4 z = ld4(zx + (size_t)m * D_PROJC + tid * 4);
  float4 g;
  g.x = y.x * silu_(z.x); g.y = y.y * silu_(z.y);
  g.z = y.z * silu_(z.z); g.w = y.w * silu_(z.w);
  float ss = g.x * g.x + g.y * g.y + g.z * g.z + g.w * g.w;
#pragma unroll
  for (int off = 32; off >= 1; off >>= 1) ss += __shfl_xor(ss, off);
  __shared__ float red[4];
  int wid = tid >> 6;
  if ((tid & 63) == 0) red[wid] = ss;
  __syncthreads();
  float tot = red[0] + red[1] + red[2] + red[3];
  float scale = rsqrtf(tot * (1.f / 1024.f) + 1e-5f);
  float4 w = *(const float4*)(norm_w + tid * 4);
  g.x *= scale * w.x; g.y *= scale * w.y; g.z *= scale * w.z; g.w *= scale * w.w;
  st4(ybuf + (size_t)m * D_INNERC + tid * 4, g);
}

// ---------------------------------------------------------------------------
extern "C" void kernel_launch(void* const* d_in, const int* in_sizes, int n_in,
                              void* d_out, int out_size, void* d_ws, size_t ws_size,
                              hipStream_t stream)
{
  const float* x         = (const float*)d_in[0];
  const float* in_proj_w = (const float*)d_in[1];
  const float* conv_w    = (const float*)d_in[2];
  const float* conv_b    = (const float*)d_in[3];
  const float* dt_bias   = (const float*)d_in[4];
  const float* A_log     = (const float*)d_in[5];
  const float* D_skip    = (const float*)d_in[6];
  const float* norm_w    = (const float*)d_in[7];
  const float* ssm_out_w = (const float*)d_in[8];
  const float* fuse_w    = (const float*)d_in[9];
  const float* fuse_b    = (const float*)d_in[10];
  float* out = (float*)d_out;

  // workspace layout — total ~227 MB
  bfu* zx     = (bfu*)d_ws;                          // 16384 x 2320 bf16
  bfu* xBC    = zx     + (size_t)M_ROWS * D_PROJC;   // 16384 x 1280 bf16
  bfu* states = xBC    + (size_t)M_ROWS * CONV_DIMC; // 2*128*16*64*128 bf16
  bfu* ybuf   = states + (size_t)33554432;           // 16384 x 1024 bf16
  float* acum = (float*)(ybuf + (size_t)M_ROWS * D_INNERC); // 2*128*16*64 f32
  float* dtg  = acum + 262144;
  float* wcmb = dtg  + 262144;                       // 2 x 512 x 1024 f32
  float* ssmT = wcmb + 1048576;                      // 1024 x 512 f32

  // Folded output weights: W_dir[o][j] = sum_k fuse_w[o, dir*512+k] * ssm_out_w[k, j]
  transpose_k<<<2048, 256, 0, stream>>>(ssm_out_w, ssmT);
  gemm_nt<float, float, float><<<dim3(8, 4), 256, 0, stream>>>(
      fuse_w, 1024, ssmT, 512, wcmb, 1024, 512, 1024, 512, nullptr, 0);
  gemm_nt<float, float, float><<<dim3(8, 4), 256, 0, stream>>>(
      fuse_w + 512, 1024, ssmT, 512, wcmb + 524288, 1024, 512, 1024, 512, nullptr, 0);
  // in_proj: zx = x @ in_proj_w^T (bf16 out)
  gemm_nt<float, float, bfu><<<dim3(19, 128), 256, 0, stream>>>(
      x, 512, in_proj_w, 512, zx, D_PROJC, M_ROWS, D_PROJC, 512, nullptr, 0);

  for (int dir = 0; dir < 2; ++dir) {
    conv_k<<<dim3(5, M_ROWS), 256, 0, stream>>>(zx, conv_w, conv_b, xBC, dir);
    states_k<<<4096, 256, 0, stream>>>(zx, xBC, dt_bias, A_log, acum, dtg, states, dir);
    scan_k<<<256, 256, 0, stream>>>(states, acum);
    y_k<<<4096, 256, 0, stream>>>(xBC, states, acum, dtg, D_skip, ybuf, dir);
    norm_k<<<M_ROWS, 256, 0, stream>>>(ybuf, zx, norm_w);
    gemm_nt<bfu, float, float><<<dim3(4, 128), 256, 0, stream>>>(
        ybuf, 1024, wcmb + (size_t)dir * 524288, 1024, out, 512,
        M_ROWS, 512, 1024, dir == 0 ? fuse_b : nullptr, dir == 0 ? 0 : 1);
  }
}

// Round 3
// 1569.436 us; speedup vs baseline: 1.4215x; 1.4215x over previous
//
#include <hip/hip_runtime.h>
#include <cstddef>

// Problem constants
#define B_SZ     2
#define L_SEQ    8192
#define D_INNERC 1024
#define NHEADSC  16
#define CHUNKC   64
#define NCHUNKC  128          // L_SEQ / CHUNK
#define CONV_DIMC 1280
#define D_PROJC  2320
#define M_ROWS   16384        // B_SZ * L_SEQ
#define NPADW    2432         // in_proj_w rows padded to multiple of 128

typedef unsigned short bfu;   // raw bf16 bits

using bf16x8 = __attribute__((ext_vector_type(8))) short;
using f32x4  = __attribute__((ext_vector_type(4))) float;

__device__ __forceinline__ float silu_(float v) { return v / (1.f + expf(-v)); }

__device__ __forceinline__ float b2f(bfu u) {
  return __uint_as_float((unsigned)u << 16);
}
__device__ __forceinline__ bfu f2b(float f) {
  unsigned x = __float_as_uint(f);
  return (bfu)((x + 0x7fffu + ((x >> 16) & 1u)) >> 16);   // RNE
}

// --- generic 4-wide load/store (fp32 or bf16 storage, fp32 values) ---------
__device__ __forceinline__ float4 ld4(const float* p) { return *(const float4*)p; }
__device__ __forceinline__ float4 ld4(const bfu* p) {
  ushort4 u = *(const ushort4*)p;
  float4 f;
  f.x = b2f(u.x); f.y = b2f(u.y); f.z = b2f(u.z); f.w = b2f(u.w);
  return f;
}
__device__ __forceinline__ void st4(float* p, float4 v) { *(float4*)p = v; }
__device__ __forceinline__ void st4(bfu* p, float4 v) {
  ushort4 u;
  u.x = f2b(v.x); u.y = f2b(v.y); u.z = f2b(v.z); u.w = f2b(v.w);
  *(ushort4*)p = u;
}
__device__ __forceinline__ float ld1(const float* p) { return *p; }
__device__ __forceinline__ float ld1(const bfu* p) { return b2f(*p); }
__device__ __forceinline__ void st1(float* p, float v) { *p = v; }
__device__ __forceinline__ void st1(bfu* p, float v) { *p = f2b(v); }

// async global->LDS, 16 B per lane; LDS dest = wave-uniform base + lane*16
__device__ __forceinline__ void gl_lds16(const bfu* g, bfu* l) {
  __builtin_amdgcn_global_load_lds(
      (const __attribute__((address_space(1))) unsigned int*)g,
      (__attribute__((address_space(3))) unsigned int*)l, 16, 0, 0);
}

// pos in original time order for (b, chunk c, local l) of direction dir
__device__ __forceinline__ int pos_of(int b, int c, int l, int dir) {
  int t = c * CHUNKC + l;
  return dir ? (b * L_SEQ + (L_SEQ - 1) - t) : (b * L_SEQ + t);
}

// ---------------------------------------------------------------------------
// MFMA GEMM (NT): C[m][n] = sum_k A[m][k] * Bw[n][k].  A,B bf16, K-contig.
// 128x128 tile, BK=32, 256 threads = 4 waves in 2x2, each wave 4x4 MFMAs of
// 16x16x32.  M % 128 == 0, K % 32 == 0, B padded so n0+127 is loadable.
// mode: 0 -> store bf16;  1 -> store f32 (+bias if given);  2 -> f32 +=
// LDS swizzle: element (row r, colgroup cg of 8 bf16) stored at byte
// r*64 + (cg ^ ((r>>1)&3))*16  ->  frag ds_read_b128 is 2-way aliased (free).
// ---------------------------------------------------------------------------
__global__ __launch_bounds__(256)
void mfma_nt(const bfu* __restrict__ A, int lda,
             const bfu* __restrict__ Bw, int ldb,
             void* __restrict__ Cv, int ldc,
             int N, int K, const float* __restrict__ bias, int mode)
{
  __shared__ bfu As[128 * 32];
  __shared__ bfu Bs[128 * 32];
  const int tid  = threadIdx.x;
  const int lane = tid & 63;
  const int wave = __builtin_amdgcn_readfirstlane(tid >> 6);
  const int wm = wave & 1, wn = wave >> 1;
  const int m0 = blockIdx.y * 128, n0 = blockIdx.x * 128;

  f32x4 acc[4][4];
#pragma unroll
  for (int i = 0; i < 4; ++i)
#pragma unroll
    for (int j = 0; j < 4; ++j)
      acc[i][j] = (f32x4){0.f, 0.f, 0.f, 0.f};

  // staging: wave handles 16-row slices {2*wave, 2*wave+1} of both tiles
  const int srow = lane >> 2;          // 0..15 within slice
  const int scgp = lane & 3;           // stored colgroup slot

  for (int k0 = 0; k0 < K; k0 += 32) {
    __syncthreads();
#pragma unroll
    for (int si = 0; si < 2; ++si) {
      int s = wave * 2 + si;
      int r = s * 16 + srow;                       // tile row 0..127
      int cg = scgp ^ ((r >> 1) & 3);              // logical colgroup
      gl_lds16(A  + (size_t)(m0 + r) * lda + k0 + cg * 8, As + s * 512);
      gl_lds16(Bw + (size_t)(n0 + r) * ldb + k0 + cg * 8, Bs + s * 512);
    }
    __syncthreads();

    bf16x8 af[4], bfr[4];
#pragma unroll
    for (int i = 0; i < 4; ++i) {
      int ra = wm * 64 + i * 16 + (lane & 15);
      int ca = (lane >> 4) ^ ((ra >> 1) & 3);
      af[i] = *(const bf16x8*)(As + ra * 32 + ca * 8);
      int rb = wn * 64 + i * 16 + (lane & 15);
      int cb = (lane >> 4) ^ ((rb >> 1) & 3);
      bfr[i] = *(const bf16x8*)(Bs + rb * 32 + cb * 8);
    }
#pragma unroll
    for (int i = 0; i < 4; ++i)
#pragma unroll
      for (int j = 0; j < 4; ++j)
        acc[i][j] = __builtin_amdgcn_mfma_f32_16x16x32_bf16(af[i], bfr[j], acc[i][j], 0, 0, 0);
  }

  // C/D layout: col = lane&15, row = (lane>>4)*4 + reg   [m89/m91 verified]
#pragma unroll
  for (int i = 0; i < 4; ++i) {
    int mbase = m0 + wm * 64 + i * 16 + (lane >> 4) * 4;
#pragma unroll
    for (int j = 0; j < 4; ++j) {
      int n = n0 + wn * 64 + j * 16 + (lane & 15);
      if (n < N) {
#pragma unroll
        for (int r = 0; r < 4; ++r) {
          float v = acc[i][j][r];
          size_t off = (size_t)(mbase + r) * ldc + n;
          if (mode == 0) {
            ((bfu*)Cv)[off] = f2b(v);
          } else {
            float* cp = (float*)Cv + off;
            if (mode == 2) v += *cp;
            else if (bias) v += bias[n];
            *cp = v;
          }
        }
      }
    }
  }
}

// ---------------------------------------------------------------------------
// fp32 vector GEMM (NT) — used only for tiny setup GEMMs now.
// ---------------------------------------------------------------------------
template <typename TA, typename TB, typename TC>
__global__ __launch_bounds__(256)
void gemm_nt(const TA* __restrict__ A, int lda,
             const TB* __restrict__ Bw, int ldb,
             TC* __restrict__ C, int ldc,
             int M, int N, int K,
             const float* __restrict__ bias, int accum)
{
  __shared__ float As[16][132];
  __shared__ float Bs[16][132];
  const int tid = threadIdx.x;
  const int n0 = blockIdx.x * 128;
  const int m0 = blockIdx.y * 128;
  const int tx = tid & 15, ty = tid >> 4;
  float acc[8][8] = {};

  for (int k0 = 0; k0 < K; k0 += 16) {
#pragma unroll
    for (int r = 0; r < 2; ++r) {
      int q = tid + r * 256;
      int row = q >> 2, cc = (q & 3) << 2;
      float4 va = ld4(A + (size_t)(m0 + row) * lda + k0 + cc);
      As[cc + 0][row] = va.x; As[cc + 1][row] = va.y;
      As[cc + 2][row] = va.z; As[cc + 3][row] = va.w;
      float4 vb = {0.f, 0.f, 0.f, 0.f};
      if (n0 + row < N)
        vb = ld4(Bw + (size_t)(n0 + row) * ldb + k0 + cc);
      Bs[cc + 0][row] = vb.x; Bs[cc + 1][row] = vb.y;
      Bs[cc + 2][row] = vb.z; Bs[cc + 3][row] = vb.w;
    }
    __syncthreads();
#pragma unroll
    for (int kk = 0; kk < 16; ++kk) {
      float a[8], b[8];
      *(float4*)(a)     = *(float4*)&As[kk][ty * 8];
      *(float4*)(a + 4) = *(float4*)&As[kk][ty * 8 + 4];
      *(float4*)(b)     = *(float4*)&Bs[kk][tx * 8];
      *(float4*)(b + 4) = *(float4*)&Bs[kk][tx * 8 + 4];
#pragma unroll
      for (int i = 0; i < 8; ++i)
#pragma unroll
        for (int j = 0; j < 8; ++j)
          acc[i][j] += a[i] * b[j];
    }
    __syncthreads();
  }

  const bool full = (n0 + 128 <= N);
#pragma unroll
  for (int i = 0; i < 8; ++i) {
    int m = m0 + ty * 8 + i;
    TC* crow = C + (size_t)m * ldc;
    int n = n0 + tx * 8;
    if (full) {
      float4 v0, v1;
      v0.x = acc[i][0]; v0.y = acc[i][1]; v0.z = acc[i][2]; v0.w = acc[i][3];
      v1.x = acc[i][4]; v1.y = acc[i][5]; v1.z = acc[i][6]; v1.w = acc[i][7];
      if (accum) {
        float4 o0 = ld4(crow + n), o1 = ld4(crow + n + 4);
        v0.x += o0.x; v0.y += o0.y; v0.z += o0.z; v0.w += o0.w;
        v1.x += o1.x; v1.y += o1.y; v1.z += o1.z; v1.w += o1.w;
      } else if (bias) {
        v0.x += bias[n + 0]; v0.y += bias[n + 1]; v0.z += bias[n + 2]; v0.w += bias[n + 3];
        v1.x += bias[n + 4]; v1.y += bias[n + 5]; v1.z += bias[n + 6]; v1.w += bias[n + 7];
      }
      st4(crow + n, v0);
      st4(crow + n + 4, v1);
    } else {
#pragma unroll
      for (int j = 0; j < 8; ++j) {
        int nn = n + j;
        if (nn < N) {
          float v = acc[i][j];
          if (accum) v += ld1(crow + nn);
          else if (bias) v += bias[nn];
          st1(crow + nn, v);
        }
      }
    }
  }
}

// ---------------------------------------------------------------------------
// fp32 -> bf16 converts
// ---------------------------------------------------------------------------
__global__ __launch_bounds__(256)
void cvt_x_k(const float* __restrict__ in, bfu* __restrict__ out)
{
  int q = blockIdx.x * 256 + threadIdx.x;     // 4-elem groups, 2,097,152 total
  st4(out + (size_t)q * 4, ld4(in + (size_t)q * 4));
}

__global__ __launch_bounds__(256)
void cvt_w_k(const float* __restrict__ in, bfu* __restrict__ out)
{
  int q = blockIdx.x * 256 + threadIdx.x;     // 0 .. 311295
  int row = q >> 7, c4 = (q & 127) << 2;
  float4 v = {0.f, 0.f, 0.f, 0.f};
  if (row < D_PROJC) v = ld4(in + (size_t)row * 512 + c4);
  st4(out + (size_t)row * 512 + c4, v);
}

// ---------------------------------------------------------------------------
// Transpose ssm_out_w (512 x 1024) -> ssmT (1024 x 512)
// ---------------------------------------------------------------------------
__global__ __launch_bounds__(256)
void transpose_k(const float* __restrict__ in, float* __restrict__ out)
{
  int idx = blockIdx.x * 256 + threadIdx.x;   // 0 .. 524287
  int j = idx >> 9, k = idx & 511;
  out[idx] = in[k * 1024 + j];
}

// ---------------------------------------------------------------------------
// Depthwise causal (dir=0) / anti-causal (dir=1) conv + bias + SiLU
// ---------------------------------------------------------------------------
__global__ __launch_bounds__(256)
void conv_k(const bfu* __restrict__ zx, const float* __restrict__ conv_w,
            const float* __restrict__ conv_b, bfu* __restrict__ xBC, int dir)
{
  int ch = blockIdx.x * 256 + threadIdx.x;   // 0..1279
  int m  = blockIdx.y;                       // 0..16383
  int t  = m & (L_SEQ - 1), b = m >> 13;
  float w0 = conv_w[ch * 4 + 0], w1 = conv_w[ch * 4 + 1];
  float w2 = conv_w[ch * 4 + 2], w3 = conv_w[ch * 4 + 3];
  float acc = conv_b[ch];
  const bfu* src = zx + 1024 + ch;
#pragma unroll
  for (int k = 0; k < 4; ++k) {
    int tt = dir ? (t + 3 - k) : (t - 3 + k);
    float w = (k == 0) ? w0 : (k == 1) ? w1 : (k == 2) ? w2 : w3;
    if (tt >= 0 && tt < L_SEQ)
      acc += w * b2f(src[(size_t)(b * L_SEQ + tt) * D_PROJC]);
  }
  xBC[(size_t)m * CONV_DIMC + ch] = f2b(silu_(acc));
}

// ---------------------------------------------------------------------------
// Per (b, chunk, head): dt/softplus, within-chunk cumsum of A*dt,
// chunk states[p][n] = sum_l B[l][n] * exp(acum[63]-acum[l]) * dt[l] * xh[l][p]
// ---------------------------------------------------------------------------
__global__ __launch_bounds__(256)
void states_k(const bfu* __restrict__ zx, const bfu* __restrict__ xBC,
              const float* __restrict__ dt_bias, const float* __restrict__ A_log,
              float* __restrict__ acum_g, float* __restrict__ dt_g,
              bfu* __restrict__ states, int dir)
{
  __shared__ float xs[64 * 64];     // x * dt * decay, [l][p]
  __shared__ float Bsh[64 * 128];   // [l][n]
  __shared__ float s_scale[64];
  int bid = blockIdx.x;
  int h = bid & 15, c = (bid >> 4) & 127, b = bid >> 11;
  int tid = threadIdx.x;

  if (tid < 64) {
    int l = tid;
    int pos = pos_of(b, c, l, dir);
    float dtr = b2f(zx[(size_t)pos * D_PROJC + 2304 + h]) + dt_bias[h];
    float dt = (dtr > 20.f) ? dtr : log1pf(expf(dtr));
    float a = -expf(A_log[h]) * dt;
#pragma unroll
    for (int off = 1; off < 64; off <<= 1) {
      float v = __shfl_up(a, off);
      if (l >= off) a += v;
    }
    float alast = __shfl(a, 63);
    s_scale[l] = dt * expf(alast - a);
    int gi = ((b * NCHUNKC + c) * NHEADSC + h) * 64 + l;
    acum_g[gi] = a; dt_g[gi] = dt;
  }
  __syncthreads();

#pragma unroll
  for (int r = 0; r < 4; ++r) {
    int q = tid + r * 256;
    int row = q >> 4, cc = (q & 15) << 2;
    int pos = pos_of(b, c, row, dir);
    float4 v = ld4(xBC + (size_t)pos * CONV_DIMC + h * 64 + cc);
    float sc = s_scale[row];
    v.x *= sc; v.y *= sc; v.z *= sc; v.w *= sc;
    *(float4*)&xs[row * 64 + cc] = v;
  }
#pragma unroll
  for (int r = 0; r < 8; ++r) {
    int q = tid + r * 256;
    int row = q >> 5, cc = (q & 31) << 2;
    int pos = pos_of(b, c, row, dir);
    *(float4*)&Bsh[row * 128 + cc] = ld4(xBC + (size_t)pos * CONV_DIMC + 1024 + cc);
  }
  __syncthreads();

  int tn = tid & 15, tp = tid >> 4;
  float acc[4][8] = {};
  for (int l = 0; l < 64; ++l) {
    float a4[4], b8[8];
    *(float4*)a4       = *(float4*)&xs[l * 64 + tp * 4];
    *(float4*)(b8)     = *(float4*)&Bsh[l * 128 + tn * 8];
    *(float4*)(b8 + 4) = *(float4*)&Bsh[l * 128 + tn * 8 + 4];
#pragma unroll
    for (int i = 0; i < 4; ++i)
#pragma unroll
      for (int j = 0; j < 8; ++j)
        acc[i][j] += a4[i] * b8[j];
  }
  size_t base = ((size_t)(b * NCHUNKC + c) * NHEADSC + h) * 8192;
#pragma unroll
  for (int i = 0; i < 4; ++i) {
    int p = tp * 4 + i;
    float4 v0, v1;
    v0.x = acc[i][0]; v0.y = acc[i][1]; v0.z = acc[i][2]; v0.w = acc[i][3];
    v1.x = acc[i][4]; v1.y = acc[i][5]; v1.z = acc[i][6]; v1.w = acc[i][7];
    st4(states + base + p * 128 + tn * 8, v0);
    st4(states + base + p * 128 + tn * 8 + 4, v1);
  }
}

// ---------------------------------------------------------------------------
// Inter-chunk scan (prefix in fp32 registers). 256 blocks: (b,h,eb)
// ---------------------------------------------------------------------------
__global__ __launch_bounds__(256)
void scan_k(bfu* __restrict__ states, const float* __restrict__ acum_g)
{
  int bid = blockIdx.x;
  int eb = bid & 7, h = (bid >> 3) & 15, b = bid >> 7;
  int e = eb * 1024 + threadIdx.x * 4;
  float4 pre = {0.f, 0.f, 0.f, 0.f};
  for (int c = 0; c < NCHUNKC; ++c) {
    size_t base = ((size_t)(b * NCHUNKC + c) * NHEADSC + h) * 8192;
    float d = expf(acum_g[((b * NCHUNKC + c) * NHEADSC + h) * 64 + 63]);
    float4 v = ld4(states + base + e);
    st4(states + base + e, pre);
    pre.x = v.x + d * pre.x; pre.y = v.y + d * pre.y;
    pre.z = v.z + d * pre.z; pre.w = v.w + d * pre.w;
  }
}

// ---------------------------------------------------------------------------
// Per (b, chunk, head): Y = (L o C B^T) * dt @ xh + exp(acum) * (C @ prefix^T)
//                          + D_skip * xh     -> ybuf (original time order)
// ---------------------------------------------------------------------------
__global__ __launch_bounds__(256)
void y_k(const bfu* __restrict__ xBC, const bfu* __restrict__ states,
         const float* __restrict__ acum_g, const float* __restrict__ dt_g,
         const float* __restrict__ D_skip, bfu* __restrict__ ybuf, int dir)
{
  __shared__ float smem[11008];
  __shared__ float s_acum[64], s_dt[64];
  float* Cs  = smem;              // 64 x 36
  float* Bs2 = smem + 2304;       // 64 x 36
  float* Ps  = smem + 4608;       // 64 x 36
  float* xh  = smem + 6912;       // 64 x 64
  float* sc  = smem;              // 64 x 68 (overlay)

  int bid = blockIdx.x;
  int h = bid & 15, c = (bid >> 4) & 127, b = bid >> 11;
  int tid = threadIdx.x;
  if (tid < 64) {
    int gi = ((b * NCHUNKC + c) * NHEADSC + h) * 64 + tid;
    s_acum[tid] = acum_g[gi]; s_dt[tid] = dt_g[gi];
  }
#pragma unroll
  for (int r = 0; r < 4; ++r) {
    int q = tid + r * 256;
    int row = q >> 4, cc = (q & 15) << 2;
    int pos = pos_of(b, c, row, dir);
    *(float4*)&xh[row * 64 + cc] = ld4(xBC + (size_t)pos * CONV_DIMC + h * 64 + cc);
  }

  int ts = tid & 15, tl = tid >> 4;
  float sacc[4][4] = {}, yacc[4][4] = {};
  size_t pbase = ((size_t)(b * NCHUNKC + c) * NHEADSC + h) * 8192;

  for (int nc = 0; nc < 4; ++nc) {
    __syncthreads();
#pragma unroll
    for (int r = 0; r < 2; ++r) {
      int q = tid + r * 256;
      int row = q >> 3, cc = (q & 7) << 2;
      int pos = pos_of(b, c, row, dir);
      *(float4*)&Cs[row * 36 + cc]  = ld4(xBC + (size_t)pos * CONV_DIMC + 1152 + nc * 32 + cc);
      *(float4*)&Bs2[row * 36 + cc] = ld4(xBC + (size_t)pos * CONV_DIMC + 1024 + nc * 32 + cc);
      *(float4*)&Ps[row * 36 + cc]  = ld4(states + pbase + row * 128 + nc * 32 + cc);
    }
    __syncthreads();
#pragma unroll
    for (int nn = 0; nn < 32; nn += 4) {
      float cf[4][4], bf[4][4], pf[4][4];
#pragma unroll
      for (int i = 0; i < 4; ++i)
        *(float4*)cf[i] = *(float4*)&Cs[(tl * 4 + i) * 36 + nn];
#pragma unroll
      for (int j = 0; j < 4; ++j) {
        *(float4*)bf[j] = *(float4*)&Bs2[(ts * 4 + j) * 36 + nn];
        *(float4*)pf[j] = *(float4*)&Ps[(ts * 4 + j) * 36 + nn];
      }
#pragma unroll
      for (int i = 0; i < 4; ++i)
#pragma unroll
        for (int j = 0; j < 4; ++j)
#pragma unroll
          for (int k = 0; k < 4; ++k) {
            sacc[i][j] += cf[i][k] * bf[j][k];
            yacc[i][j] += cf[i][k] * pf[j][k];
          }
    }
  }
  __syncthreads();
#pragma unroll
  for (int i = 0; i < 4; ++i)
#pragma unroll
    for (int j = 0; j < 4; ++j) {
      int l = tl * 4 + i, s = ts * 4 + j;
      float v = 0.f;
      if (s <= l) v = sacc[i][j] * expf(s_acum[l] - s_acum[s]) * s_dt[s];
      sc[l * 68 + s] = v;
    }
  __syncthreads();

  float Dh = D_skip[h];
  float yout[4][4];
#pragma unroll
  for (int i = 0; i < 4; ++i) {
    int l = tl * 4 + i;
    float dec = expf(s_acum[l]);
#pragma unroll
    for (int j = 0; j < 4; ++j) {
      int p = ts * 4 + j;
      yout[i][j] = yacc[i][j] * dec + Dh * xh[l * 64 + p];
    }
  }
#pragma unroll
  for (int s4 = 0; s4 < 64; s4 += 4) {
    float sf[4][4], xf[4][4];
#pragma unroll
    for (int i = 0; i < 4; ++i)
      *(float4*)sf[i] = *(float4*)&sc[(tl * 4 + i) * 68 + s4];
#pragma unroll
    for (int k = 0; k < 4; ++k)
      *(float4*)xf[k] = *(float4*)&xh[(s4 + k) * 64 + ts * 4];
#pragma unroll
    for (int i = 0; i < 4; ++i)
#pragma unroll
      for (int j = 0; j < 4; ++j)
#pragma unroll
        for (int k = 0; k < 4; ++k)
          yout[i][j] += sf[i][k] * xf[k][j];
  }
#pragma unroll
  for (int i = 0; i < 4; ++i) {
    int l = tl * 4 + i;
    int pos = pos_of(b, c, l, dir);
    float4 v; v.x = yout[i][0]; v.y = yout[i][1]; v.z = yout[i][2]; v.w = yout[i][3];
    st4(ybuf + (size_t)pos * D_INNERC + h * 64 + ts * 4, v);
  }
}

// ---------------------------------------------------------------------------
// Gating (y *= silu(z)) + RMSNorm over 1024 + norm_w, in place on ybuf (bf16)
// ---------------------------------------------------------------------------
__global__ __launch_bounds__(256)
void norm_k(bfu* __restrict__ ybuf, const bfu* __restrict__ zx,
            const float* __restrict__ norm_w)
{
  int m = blockIdx.x, tid = threadIdx.x;
  float4 y = ld4(ybuf + (size_t)m * D_INNERC + tid * 4);
  float4 z = ld4(zx + (size_t)m * D_PROJC + tid * 4);
  float4 g;
  g.x = y.x * silu_(z.x); g.y = y.y * silu_(z.y);
  g.z = y.z * silu_(z.z); g.w = y.w * silu_(z.w);
  float ss = g.x * g.x + g.y * g.y + g.z * g.z + g.w * g.w;
#pragma unroll
  for (int off = 32; off >= 1; off >>= 1) ss += __shfl_xor(ss, off);
  __shared__ float red[4];
  int wid = tid >> 6;
  if ((tid & 63) == 0) red[wid] = ss;
  __syncthreads();
  float tot = red[0] + red[1] + red[2] + red[3];
  float scale = rsqrtf(tot * (1.f / 1024.f) + 1e-5f);
  float4 w = *(const float4*)(norm_w + tid * 4);
  g.x *= scale * w.x; g.y *= scale * w.y; g.z *= scale * w.z; g.w *= scale * w.w;
  st4(ybuf + (size_t)m * D_INNERC + tid * 4, g);
}

// ---------------------------------------------------------------------------
extern "C" void kernel_launch(void* const* d_in, const int* in_sizes, int n_in,
                              void* d_out, int out_size, void* d_ws, size_t ws_size,
                              hipStream_t stream)
{
  const float* x         = (const float*)d_in[0];
  const float* in_proj_w = (const float*)d_in[1];
  const float* conv_w    = (const float*)d_in[2];
  const float* conv_b    = (const float*)d_in[3];
  const float* dt_bias   = (const float*)d_in[4];
  const float* A_log     = (const float*)d_in[5];
  const float* D_skip    = (const float*)d_in[6];
  const float* norm_w    = (const float*)d_in[7];
  const float* ssm_out_w = (const float*)d_in[8];
  const float* fuse_w    = (const float*)d_in[9];
  const float* fuse_b    = (const float*)d_in[10];
  float* out = (float*)d_out;

  // workspace layout — ~225 MB
  bfu* zx     = (bfu*)d_ws;                          // 16384 x 2320 bf16
  bfu* xBC    = zx     + (size_t)M_ROWS * D_PROJC;   // 16384 x 1280 bf16
  bfu* states = xBC    + (size_t)M_ROWS * CONV_DIMC; // 33,554,432 bf16
  bfu* ybuf   = states + (size_t)33554432;           // 16384 x 1024 bf16
  float* acum = (float*)(ybuf + (size_t)M_ROWS * D_INNERC); // 262144 f32
  float* dtg  = acum + 262144;                       // 262144 f32
  float* ssmT = dtg  + 262144;                       // 1024 x 512 f32
  bfu* wcmb   = (bfu*)(ssmT + 524288);               // 2 x 512 x 1024 bf16
  // transient aliases inside the states region (dead before states_k runs):
  bfu* xb = states;                    // 16384 x 512 bf16  (8,388,608)
  bfu* wb = states + 8388608;          // 2432  x 512 bf16  (1,245,184)

  // bf16 copies of GEMM inputs
  cvt_x_k<<<8192, 256, 0, stream>>>(x, xb);
  cvt_w_k<<<1216, 256, 0, stream>>>(in_proj_w, wb);

  // Folded output weights: wcmb[dir][o][j] = sum_k fuse_w[o, dir*512+k] * ssm_out_w[k, j]
  transpose_k<<<2048, 256, 0, stream>>>(ssm_out_w, ssmT);
  gemm_nt<float, float, bfu><<<dim3(8, 4), 256, 0, stream>>>(
      fuse_w, 1024, ssmT, 512, wcmb, 1024, 512, 1024, 512, nullptr, 0);
  gemm_nt<float, float, bfu><<<dim3(8, 4), 256, 0, stream>>>(
      fuse_w + 512, 1024, ssmT, 512, wcmb + 524288, 1024, 512, 1024, 512, nullptr, 0);

  // in_proj: zx = x @ in_proj_w^T  (MFMA bf16, fp32 acc, bf16 out)
  mfma_nt<<<dim3(19, 128), 256, 0, stream>>>(
      xb, 512, wb, 512, zx, D_PROJC, D_PROJC, 512, nullptr, 0);

  for (int dir = 0; dir < 2; ++dir) {
    conv_k<<<dim3(5, M_ROWS), 256, 0, stream>>>(zx, conv_w, conv_b, xBC, dir);
    states_k<<<4096, 256, 0, stream>>>(zx, xBC, dt_bias, A_log, acum, dtg, states, dir);
    scan_k<<<256, 256, 0, stream>>>(states, acum);
    y_k<<<4096, 256, 0, stream>>>(xBC, states, acum, dtg, D_skip, ybuf, dir);
    norm_k<<<M_ROWS, 256, 0, stream>>>(ybuf, zx, norm_w);
    // out += ynorm @ wcmb[dir]^T   (MFMA)
    mfma_nt<<<dim3(4, 128), 256, 0, stream>>>(
        ybuf, 1024, wcmb + (size_t)dir * 524288, 1024, out, 512,
        512, 1024, dir == 0 ? fuse_b : nullptr, dir == 0 ? 1 : 2);
  }
}

// Round 4
// 846.040 us; speedup vs baseline: 2.6370x; 1.8550x over previous
//
#include <hip/hip_runtime.h>
#include <cstddef>

// Problem constants
#define B_SZ     2
#define L_SEQ    8192
#define D_INNERC 1024
#define NHEADSC  16
#define CHUNKC   64
#define NCHUNKC  128          // L_SEQ / CHUNK
#define CONV_DIMC 1280
#define D_PROJC  2320
#define M_ROWS   16384        // B_SZ * L_SEQ

typedef unsigned short bfu;   // raw bf16 bits

using bf16x8 = __attribute__((ext_vector_type(8))) short;
using f32x4  = __attribute__((ext_vector_type(4))) float;

__device__ __forceinline__ float silu_(float v) { return v / (1.f + expf(-v)); }

__device__ __forceinline__ float b2f(bfu u) {
  return __uint_as_float((unsigned)u << 16);
}
__device__ __forceinline__ bfu f2b(float f) {
  unsigned x = __float_as_uint(f);
  return (bfu)((x + 0x7fffu + ((x >> 16) & 1u)) >> 16);   // RNE
}

__device__ __forceinline__ float4 ld4(const float* p) { return *(const float4*)p; }
__device__ __forceinline__ float4 ld4(const bfu* p) {
  ushort4 u = *(const ushort4*)p;
  float4 f;
  f.x = b2f(u.x); f.y = b2f(u.y); f.z = b2f(u.z); f.w = b2f(u.w);
  return f;
}
__device__ __forceinline__ void st4(float* p, float4 v) { *(float4*)p = v; }
__device__ __forceinline__ void st4(bfu* p, float4 v) {
  ushort4 u;
  u.x = f2b(v.x); u.y = f2b(v.y); u.z = f2b(v.z); u.w = f2b(v.w);
  *(ushort4*)p = u;
}
__device__ __forceinline__ float ld1(const float* p) { return *p; }
__device__ __forceinline__ float ld1(const bfu* p) { return b2f(*p); }
__device__ __forceinline__ void st1(float* p, float v) { *p = v; }
__device__ __forceinline__ void st1(bfu* p, float v) { *p = f2b(v); }

__device__ __forceinline__ void gl_lds16(const bfu* g, bfu* l) {
  __builtin_amdgcn_global_load_lds(
      (const __attribute__((address_space(1))) unsigned int*)g,
      (__attribute__((address_space(3))) unsigned int*)l, 16, 0, 0);
}

__device__ __forceinline__ int pos_of(int b, int c, int l, int dir) {
  int t = c * CHUNKC + l;
  return dir ? (b * L_SEQ + (L_SEQ - 1) - t) : (b * L_SEQ + t);
}

// ---------------------------------------------------------------------------
// MFMA GEMM (NT) — unchanged from round 3 (verified working).
// ---------------------------------------------------------------------------
__global__ __launch_bounds__(256)
void mfma_nt(const bfu* __restrict__ A, int lda,
             const bfu* __restrict__ Bw, int ldb,
             void* __restrict__ Cv, int ldc,
             int N, int K, const float* __restrict__ bias, int mode)
{
  __shared__ bfu As[128 * 32];
  __shared__ bfu Bs[128 * 32];
  const int tid  = threadIdx.x;
  const int lane = tid & 63;
  const int wave = __builtin_amdgcn_readfirstlane(tid >> 6);
  const int wm = wave & 1, wn = wave >> 1;
  const int m0 = blockIdx.y * 128, n0 = blockIdx.x * 128;

  f32x4 acc[4][4];
#pragma unroll
  for (int i = 0; i < 4; ++i)
#pragma unroll
    for (int j = 0; j < 4; ++j)
      acc[i][j] = (f32x4){0.f, 0.f, 0.f, 0.f};

  const int srow = lane >> 2;
  const int scgp = lane & 3;

  for (int k0 = 0; k0 < K; k0 += 32) {
    __syncthreads();
#pragma unroll
    for (int si = 0; si < 2; ++si) {
      int s = wave * 2 + si;
      int r = s * 16 + srow;
      int cg = scgp ^ ((r >> 1) & 3);
      gl_lds16(A  + (size_t)(m0 + r) * lda + k0 + cg * 8, As + s * 512);
      gl_lds16(Bw + (size_t)(n0 + r) * ldb + k0 + cg * 8, Bs + s * 512);
    }
    __syncthreads();

    bf16x8 af[4], bfr[4];
#pragma unroll
    for (int i = 0; i < 4; ++i) {
      int ra = wm * 64 + i * 16 + (lane & 15);
      int ca = (lane >> 4) ^ ((ra >> 1) & 3);
      af[i] = *(const bf16x8*)(As + ra * 32 + ca * 8);
      int rb = wn * 64 + i * 16 + (lane & 15);
      int cb = (lane >> 4) ^ ((rb >> 1) & 3);
      bfr[i] = *(const bf16x8*)(Bs + rb * 32 + cb * 8);
    }
#pragma unroll
    for (int i = 0; i < 4; ++i)
#pragma unroll
      for (int j = 0; j < 4; ++j)
        acc[i][j] = __builtin_amdgcn_mfma_f32_16x16x32_bf16(af[i], bfr[j], acc[i][j], 0, 0, 0);
  }

#pragma unroll
  for (int i = 0; i < 4; ++i) {
    int mbase = m0 + wm * 64 + i * 16 + (lane >> 4) * 4;
#pragma unroll
    for (int j = 0; j < 4; ++j) {
      int n = n0 + wn * 64 + j * 16 + (lane & 15);
      if (n < N) {
#pragma unroll
        for (int r = 0; r < 4; ++r) {
          float v = acc[i][j][r];
          size_t off = (size_t)(mbase + r) * ldc + n;
          if (mode == 0) {
            ((bfu*)Cv)[off] = f2b(v);
          } else {
            float* cp = (float*)Cv + off;
            if (mode == 2) v += *cp;
            else if (bias) v += bias[n];
            *cp = v;
          }
        }
      }
    }
  }
}

// ---------------------------------------------------------------------------
// fp32 vector GEMM (NT) — tiny setup GEMMs only.
// ---------------------------------------------------------------------------
template <typename TA, typename TB, typename TC>
__global__ __launch_bounds__(256)
void gemm_nt(const TA* __restrict__ A, int lda,
             const TB* __restrict__ Bw, int ldb,
             TC* __restrict__ C, int ldc,
             int M, int N, int K,
             const float* __restrict__ bias, int accum)
{
  __shared__ float As[16][132];
  __shared__ float Bs[16][132];
  const int tid = threadIdx.x;
  const int n0 = blockIdx.x * 128;
  const int m0 = blockIdx.y * 128;
  const int tx = tid & 15, ty = tid >> 4;
  float acc[8][8] = {};

  for (int k0 = 0; k0 < K; k0 += 16) {
#pragma unroll
    for (int r = 0; r < 2; ++r) {
      int q = tid + r * 256;
      int row = q >> 2, cc = (q & 3) << 2;
      float4 va = ld4(A + (size_t)(m0 + row) * lda + k0 + cc);
      As[cc + 0][row] = va.x; As[cc + 1][row] = va.y;
      As[cc + 2][row] = va.z; As[cc + 3][row] = va.w;
      float4 vb = {0.f, 0.f, 0.f, 0.f};
      if (n0 + row < N)
        vb = ld4(Bw + (size_t)(n0 + row) * ldb + k0 + cc);
      Bs[cc + 0][row] = vb.x; Bs[cc + 1][row] = vb.y;
      Bs[cc + 2][row] = vb.z; Bs[cc + 3][row] = vb.w;
    }
    __syncthreads();
#pragma unroll
    for (int kk = 0; kk < 16; ++kk) {
      float a[8], b[8];
      *(float4*)(a)     = *(float4*)&As[kk][ty * 8];
      *(float4*)(a + 4) = *(float4*)&As[kk][ty * 8 + 4];
      *(float4*)(b)     = *(float4*)&Bs[kk][tx * 8];
      *(float4*)(b + 4) = *(float4*)&Bs[kk][tx * 8 + 4];
#pragma unroll
      for (int i = 0; i < 8; ++i)
#pragma unroll
        for (int j = 0; j < 8; ++j)
          acc[i][j] += a[i] * b[j];
    }
    __syncthreads();
  }

  const bool full = (n0 + 128 <= N);
#pragma unroll
  for (int i = 0; i < 8; ++i) {
    int m = m0 + ty * 8 + i;
    TC* crow = C + (size_t)m * ldc;
    int n = n0 + tx * 8;
    if (full) {
      float4 v0, v1;
      v0.x = acc[i][0]; v0.y = acc[i][1]; v0.z = acc[i][2]; v0.w = acc[i][3];
      v1.x = acc[i][4]; v1.y = acc[i][5]; v1.z = acc[i][6]; v1.w = acc[i][7];
      if (accum) {
        float4 o0 = ld4(crow + n), o1 = ld4(crow + n + 4);
        v0.x += o0.x; v0.y += o0.y; v0.z += o0.z; v0.w += o0.w;
        v1.x += o1.x; v1.y += o1.y; v1.z += o1.z; v1.w += o1.w;
      } else if (bias) {
        v0.x += bias[n + 0]; v0.y += bias[n + 1]; v0.z += bias[n + 2]; v0.w += bias[n + 3];
        v1.x += bias[n + 4]; v1.y += bias[n + 5]; v1.z += bias[n + 6]; v1.w += bias[n + 7];
      }
      st4(crow + n, v0);
      st4(crow + n + 4, v1);
    } else {
#pragma unroll
      for (int j = 0; j < 8; ++j) {
        int nn = n + j;
        if (nn < N) {
          float v = acc[i][j];
          if (accum) v += ld1(crow + nn);
          else if (bias) v += bias[nn];
          st1(crow + nn, v);
        }
      }
    }
  }
}

// ---------------------------------------------------------------------------
// fp32 -> bf16 converts + transpose (setup)
// ---------------------------------------------------------------------------
__global__ __launch_bounds__(256)
void cvt_x_k(const float* __restrict__ in, bfu* __restrict__ out)
{
  int q = blockIdx.x * 256 + threadIdx.x;
  st4(out + (size_t)q * 4, ld4(in + (size_t)q * 4));
}

__global__ __launch_bounds__(256)
void cvt_w_k(const float* __restrict__ in, bfu* __restrict__ out)
{
  int q = blockIdx.x * 256 + threadIdx.x;
  int row = q >> 7, c4 = (q & 127) << 2;
  float4 v = {0.f, 0.f, 0.f, 0.f};
  if (row < D_PROJC) v = ld4(in + (size_t)row * 512 + c4);
  st4(out + (size_t)row * 512 + c4, v);
}

__global__ __launch_bounds__(256)
void transpose_k(const float* __restrict__ in, float* __restrict__ out)
{
  int idx = blockIdx.x * 256 + threadIdx.x;
  int j = idx >> 9, k = idx & 511;
  out[idx] = in[k * 1024 + j];
}

// ---------------------------------------------------------------------------
// Depthwise causal / anti-causal conv + bias + SiLU
// ---------------------------------------------------------------------------
__global__ __launch_bounds__(256)
void conv_k(const bfu* __restrict__ zx, const float* __restrict__ conv_w,
            const float* __restrict__ conv_b, bfu* __restrict__ xBC, int dir)
{
  int ch = blockIdx.x * 256 + threadIdx.x;   // 0..1279
  int m  = blockIdx.y;                       // 0..16383
  int t  = m & (L_SEQ - 1), b = m >> 13;
  float w0 = conv_w[ch * 4 + 0], w1 = conv_w[ch * 4 + 1];
  float w2 = conv_w[ch * 4 + 2], w3 = conv_w[ch * 4 + 3];
  float acc = conv_b[ch];
  const bfu* src = zx + 1024 + ch;
#pragma unroll
  for (int k = 0; k < 4; ++k) {
    int tt = dir ? (t + 3 - k) : (t - 3 + k);
    float w = (k == 0) ? w0 : (k == 1) ? w1 : (k == 2) ? w2 : w3;
    if (tt >= 0 && tt < L_SEQ)
      acc += w * b2f(src[(size_t)(b * L_SEQ + tt) * D_PROJC]);
  }
  xBC[(size_t)m * CONV_DIMC + ch] = f2b(silu_(acc));
}

// ---------------------------------------------------------------------------
// MFMA states: per (b,c) block, 8 heads/block (grid 512/dir).
// states[p][n] = sum_l xh[l][p]*scale_h[l] * B[l][n] via MFMA (xsT, BT in LDS).
// Also computes per-head dt/acum scans -> acum_g, dt_g.
// ---------------------------------------------------------------------------
__global__ __launch_bounds__(256)
void states_mfma_k(const bfu* __restrict__ zx, const bfu* __restrict__ xBC,
                   const float* __restrict__ dt_bias, const float* __restrict__ A_log,
                   float* __restrict__ acum_g, float* __restrict__ dt_g,
                   bfu* __restrict__ states, int dir)
{
  __shared__ bfu BT[128 * 72];     // [n][l]
  __shared__ bfu xsT[64 * 72];     // [p][l]
  __shared__ float scaleS[8 * 64];

  int bid = blockIdx.x;
  int hb = bid >> 8;
  int c = bid & 127, b = (bid >> 7) & 1;
  int tid = threadIdx.x, lane = tid & 63;
  int w = tid >> 6, q = lane >> 4, t = lane & 15;

  // per-head scans: 4 waves x 2 rounds, one head each, lane = l
#pragma unroll
  for (int rr = 0; rr < 2; ++rr) {
    int i = w + rr * 4;
    int h = hb * 8 + i;
    int l = lane;
    int pos = pos_of(b, c, l, dir);
    float dtr = b2f(zx[(size_t)pos * D_PROJC + 2304 + h]) + dt_bias[h];
    float dt = (dtr > 20.f) ? dtr : log1pf(expf(dtr));
    float a = -expf(A_log[h]) * dt;
#pragma unroll
    for (int off = 1; off < 64; off <<= 1) {
      float v = __shfl_up(a, off);
      if (l >= off) a += v;
    }
    float alast = __shfl(a, 63);
    int gi = ((b * NCHUNKC + c) * NHEADSC + h) * 64 + l;
    acum_g[gi] = a; dt_g[gi] = dt;
    scaleS[i * 64 + l] = dt * expf(alast - a);
  }

  // stage BT[n][l] (transpose of B)
#pragma unroll
  for (int r = 0; r < 8; ++r) {
    int qq = tid + r * 256;
    int l = qq & 63, ng = qq >> 6;   // ng 0..31
    ushort4 v = *(const ushort4*)(xBC + (size_t)pos_of(b, c, l, dir) * CONV_DIMC + 1024 + ng * 4);
    BT[(ng * 4 + 0) * 72 + l] = v.x; BT[(ng * 4 + 1) * 72 + l] = v.y;
    BT[(ng * 4 + 2) * 72 + l] = v.z; BT[(ng * 4 + 3) * 72 + l] = v.w;
  }
  __syncthreads();

  for (int i = 0; i < 8; ++i) {
    int h = hb * 8 + i;
    // stage xsT[p][l] = xh[l][p] * scale[l]
#pragma unroll
    for (int r = 0; r < 4; ++r) {
      int qq = tid + r * 256;
      int l = qq & 63, pg = qq >> 6;   // pg 0..15
      float s = scaleS[i * 64 + l];
      ushort4 v = *(const ushort4*)(xBC + (size_t)pos_of(b, c, l, dir) * CONV_DIMC + h * 64 + pg * 4);
      xsT[(pg * 4 + 0) * 72 + l] = f2b(b2f(v.x) * s);
      xsT[(pg * 4 + 1) * 72 + l] = f2b(b2f(v.y) * s);
      xsT[(pg * 4 + 2) * 72 + l] = f2b(b2f(v.z) * s);
      xsT[(pg * 4 + 3) * 72 + l] = f2b(b2f(v.w) * s);
    }
    __syncthreads();

    bf16x8 axs[2];
#pragma unroll
    for (int ks = 0; ks < 2; ++ks)
      axs[ks] = *(const bf16x8*)(xsT + (w * 16 + t) * 72 + ks * 32 + q * 8);

    f32x4 acc[8];
#pragma unroll
    for (int j = 0; j < 8; ++j) acc[j] = (f32x4){0.f, 0.f, 0.f, 0.f};
#pragma unroll
    for (int ks = 0; ks < 2; ++ks)
#pragma unroll
      for (int j = 0; j < 8; ++j) {
        bf16x8 bB = *(const bf16x8*)(BT + (j * 16 + t) * 72 + ks * 32 + q * 8);
        acc[j] = __builtin_amdgcn_mfma_f32_16x16x32_bf16(axs[ks], bB, acc[j], 0, 0, 0);
      }

    size_t base = ((size_t)(b * NCHUNKC + c) * NHEADSC + h) * 8192;
#pragma unroll
    for (int j = 0; j < 8; ++j)
#pragma unroll
      for (int r = 0; r < 4; ++r) {
        int p = w * 16 + q * 4 + r, n = j * 16 + t;
        states[base + p * 128 + n] = f2b(acc[j][r]);
      }
    __syncthreads();
  }
}

// ---------------------------------------------------------------------------
// Inter-chunk scan (prefix in fp32 registers). 256 blocks: (b,h,eb)
// ---------------------------------------------------------------------------
__global__ __launch_bounds__(256)
void scan_k(bfu* __restrict__ states, const float* __restrict__ acum_g)
{
  int bid = blockIdx.x;
  int eb = bid & 7, h = (bid >> 3) & 15, b = bid >> 7;
  int e = eb * 1024 + threadIdx.x * 4;
  float4 pre = {0.f, 0.f, 0.f, 0.f};
  for (int c = 0; c < NCHUNKC; ++c) {
    size_t base = ((size_t)(b * NCHUNKC + c) * NHEADSC + h) * 8192;
    float d = expf(acum_g[((b * NCHUNKC + c) * NHEADSC + h) * 64 + 63]);
    float4 v = ld4(states + base + e);
    st4(states + base + e, pre);
    pre.x = v.x + d * pre.x; pre.y = v.y + d * pre.y;
    pre.z = v.z + d * pre.z; pre.w = v.w + d * pre.w;
  }
}

// ---------------------------------------------------------------------------
// MFMA Y: per (b,c) block, 8 heads/block (grid 512/dir).
// sacc = C@B^T once per block; per head: yacc = C@P^T; sc = mask(L)*sacc*dt
// (+D on diag) -> LDS; Y = sc@xh + yacc*exp(acum) -> ybuf.
// ---------------------------------------------------------------------------
__global__ __launch_bounds__(256)
void y_mfma_k(const bfu* __restrict__ xBC, const bfu* __restrict__ states,
              const float* __restrict__ acum_g, const float* __restrict__ dt_g,
              const float* __restrict__ D_skip, bfu* __restrict__ ybuf, int dir)
{
  __shared__ bfu smem[30976];           // 61,952 B
  bfu* Cs  = smem;                      // 64 x 136
  bfu* Bsc = smem + 8704;               // 64 x 136 (B tile; sc 64x72 overlays)
  bfu* Ps  = smem + 17408;              // 64 x 136
  bfu* xhT = smem + 26112;              // 64 x 72  [p][s]
  float* acumH = (float*)(smem + 30720);   // 64
  float* dtH   = acumH + 64;               // 64

  int bid = blockIdx.x;
  int hb = bid >> 8;
  int c = bid & 127, b = (bid >> 7) & 1;
  int tid = threadIdx.x, lane = tid & 63;
  int w = tid >> 6, q = lane >> 4, t = lane & 15;

  // stage C, B tiles (rows l, K-contig n=128, stride 136)
#pragma unroll
  for (int r = 0; r < 8; ++r) {
    int qq = tid + r * 256;
    int row = qq >> 5, grp = qq & 31;
    const bfu* src = xBC + (size_t)pos_of(b, c, row, dir) * CONV_DIMC;
    *(ushort4*)(Cs  + row * 136 + grp * 4) = *(const ushort4*)(src + 1152 + grp * 4);
    *(ushort4*)(Bsc + row * 136 + grp * 4) = *(const ushort4*)(src + 1024 + grp * 4);
  }
  __syncthreads();

  // cache A fragments (C rows of this wave) for all K-steps
  bf16x8 af[4];
#pragma unroll
  for (int ks = 0; ks < 4; ++ks)
    af[ks] = *(const bf16x8*)(Cs + (w * 16 + t) * 136 + ks * 32 + q * 8);

  // sacc = C @ B^T (once per block)
  f32x4 sacc[4];
#pragma unroll
  for (int j = 0; j < 4; ++j) sacc[j] = (f32x4){0.f, 0.f, 0.f, 0.f};
#pragma unroll
  for (int ks = 0; ks < 4; ++ks)
#pragma unroll
    for (int j = 0; j < 4; ++j) {
      bf16x8 bf = *(const bf16x8*)(Bsc + (j * 16 + t) * 136 + ks * 32 + q * 8);
      sacc[j] = __builtin_amdgcn_mfma_f32_16x16x32_bf16(af[ks], bf, sacc[j], 0, 0, 0);
    }

  for (int i = 0; i < 8; ++i) {
    int h = hb * 8 + i;
    __syncthreads();   // prior-iter LDS reads done; GEMM1's Bsc reads done
    size_t pbase = ((size_t)(b * NCHUNKC + c) * NHEADSC + h) * 8192;
#pragma unroll
    for (int r = 0; r < 8; ++r) {
      int qq = tid + r * 256;
      int row = qq >> 5, grp = qq & 31;
      *(ushort4*)(Ps + row * 136 + grp * 4) =
          *(const ushort4*)(states + pbase + row * 128 + grp * 4);
    }
#pragma unroll
    for (int r = 0; r < 4; ++r) {
      int qq = tid + r * 256;
      int l = qq & 63, pg = qq >> 6;
      ushort4 v = *(const ushort4*)(xBC + (size_t)pos_of(b, c, l, dir) * CONV_DIMC + h * 64 + pg * 4);
      xhT[(pg * 4 + 0) * 72 + l] = v.x; xhT[(pg * 4 + 1) * 72 + l] = v.y;
      xhT[(pg * 4 + 2) * 72 + l] = v.z; xhT[(pg * 4 + 3) * 72 + l] = v.w;
    }
    if (tid < 64) {
      int gi = ((b * NCHUNKC + c) * NHEADSC + h) * 64 + tid;
      acumH[tid] = acum_g[gi]; dtH[tid] = dt_g[gi];
    }
    __syncthreads();

    // yacc = C @ P^T
    f32x4 yacc[4];
#pragma unroll
    for (int j = 0; j < 4; ++j) yacc[j] = (f32x4){0.f, 0.f, 0.f, 0.f};
#pragma unroll
    for (int ks = 0; ks < 4; ++ks)
#pragma unroll
      for (int j = 0; j < 4; ++j) {
        bf16x8 bP = *(const bf16x8*)(Ps + (j * 16 + t) * 136 + ks * 32 + q * 8);
        yacc[j] = __builtin_amdgcn_mfma_f32_16x16x32_bf16(af[ks], bP, yacc[j], 0, 0, 0);
      }

    // sc = mask(L)*sacc*dt (+D_skip on diag) -> LDS (own rows, stride 72)
    float Dh = D_skip[h];
    bfu* sc = Bsc;
#pragma unroll
    for (int j = 0; j < 4; ++j)
#pragma unroll
      for (int r = 0; r < 4; ++r) {
        int l = w * 16 + q * 4 + r, s = j * 16 + t;
        float v = 0.f;
        if (s <= l) v = sacc[j][r] * expf(acumH[l] - acumH[s]) * dtH[s];
        if (s == l) v += Dh;
        sc[l * 72 + s] = f2b(v);
      }

    // acc2 init = yacc * exp(acum[l])
    f32x4 acc2[4];
    float dec[4];
#pragma unroll
    for (int r = 0; r < 4; ++r) dec[r] = expf(acumH[w * 16 + q * 4 + r]);
#pragma unroll
    for (int j = 0; j < 4; ++j)
#pragma unroll
      for (int r = 0; r < 4; ++r) acc2[j][r] = yacc[j][r] * dec[r];

    // Y += sc @ xh  (A = sc rows l, B = xhT rows p, K = s = 64)
#pragma unroll
    for (int ks = 0; ks < 2; ++ks) {
      bf16x8 asc = *(const bf16x8*)(sc + (w * 16 + t) * 72 + ks * 32 + q * 8);
#pragma unroll
      for (int j = 0; j < 4; ++j) {
        bf16x8 bx = *(const bf16x8*)(xhT + (j * 16 + t) * 72 + ks * 32 + q * 8);
        acc2[j] = __builtin_amdgcn_mfma_f32_16x16x32_bf16(asc, bx, acc2[j], 0, 0, 0);
      }
    }

    // store Y tile
#pragma unroll
    for (int j = 0; j < 4; ++j)
#pragma unroll
      for (int r = 0; r < 4; ++r) {
        int l = w * 16 + q * 4 + r, p = j * 16 + t;
        ybuf[(size_t)pos_of(b, c, l, dir) * D_INNERC + h * 64 + p] = f2b(acc2[j][r]);
      }
  }
}

// ---------------------------------------------------------------------------
// Gating (y *= silu(z)) + RMSNorm over 1024 + norm_w, in place on ybuf (bf16)
// ---------------------------------------------------------------------------
__global__ __launch_bounds__(256)
void norm_k(bfu* __restrict__ ybuf, const bfu* __restrict__ zx,
            const float* __restrict__ norm_w)
{
  int m = blockIdx.x, tid = threadIdx.x;
  float4 y = ld4(ybuf + (size_t)m * D_INNERC + tid * 4);
  float4 z = ld4(zx + (size_t)m * D_PROJC + tid * 4);
  float4 g;
  g.x = y.x * silu_(z.x); g.y = y.y * silu_(z.y);
  g.z = y.z * silu_(z.z); g.w = y.w * silu_(z.w);
  float ss = g.x * g.x + g.y * g.y + g.z * g.z + g.w * g.w;
#pragma unroll
  for (int off = 32; off >= 1; off >>= 1) ss += __shfl_xor(ss, off);
  __shared__ float red[4];
  int wid = tid >> 6;
  if ((tid & 63) == 0) red[wid] = ss;
  __syncthreads();
  float tot = red[0] + red[1] + red[2] + red[3];
  float scale = rsqrtf(tot * (1.f / 1024.f) + 1e-5f);
  float4 w = *(const float4*)(norm_w + tid * 4);
  g.x *= scale * w.x; g.y *= scale * w.y; g.z *= scale * w.z; g.w *= scale * w.w;
  st4(ybuf + (size_t)m * D_INNERC + tid * 4, g);
}

// ---------------------------------------------------------------------------
extern "C" void kernel_launch(void* const* d_in, const int* in_sizes, int n_in,
                              void* d_out, int out_size, void* d_ws, size_t ws_size,
                              hipStream_t stream)
{
  const float* x         = (const float*)d_in[0];
  const float* in_proj_w = (const float*)d_in[1];
  const float* conv_w    = (const float*)d_in[2];
  const float* conv_b    = (const float*)d_in[3];
  const float* dt_bias   = (const float*)d_in[4];
  const float* A_log     = (const float*)d_in[5];
  const float* D_skip    = (const float*)d_in[6];
  const float* norm_w    = (const float*)d_in[7];
  const float* ssm_out_w = (const float*)d_in[8];
  const float* fuse_w    = (const float*)d_in[9];
  const float* fuse_b    = (const float*)d_in[10];
  float* out = (float*)d_out;

  // workspace layout — ~225 MB
  bfu* zx     = (bfu*)d_ws;                          // 16384 x 2320 bf16
  bfu* xBC    = zx     + (size_t)M_ROWS * D_PROJC;   // 16384 x 1280 bf16
  bfu* states = xBC    + (size_t)M_ROWS * CONV_DIMC; // 33,554,432 bf16
  bfu* ybuf   = states + (size_t)33554432;           // 16384 x 1024 bf16
  float* acum = (float*)(ybuf + (size_t)M_ROWS * D_INNERC); // 262144 f32
  float* dtg  = acum + 262144;                       // 262144 f32
  float* ssmT = dtg  + 262144;                       // 1024 x 512 f32
  bfu* wcmb   = (bfu*)(ssmT + 524288);               // 2 x 512 x 1024 bf16
  // transient aliases inside the states region (dead before states_mfma_k):
  bfu* xb = states;                    // 16384 x 512 bf16
  bfu* wb = states + 8388608;          // 2432  x 512 bf16

  cvt_x_k<<<8192, 256, 0, stream>>>(x, xb);
  cvt_w_k<<<1216, 256, 0, stream>>>(in_proj_w, wb);

  transpose_k<<<2048, 256, 0, stream>>>(ssm_out_w, ssmT);
  gemm_nt<float, float, bfu><<<dim3(8, 4), 256, 0, stream>>>(
      fuse_w, 1024, ssmT, 512, wcmb, 1024, 512, 1024, 512, nullptr, 0);
  gemm_nt<float, float, bfu><<<dim3(8, 4), 256, 0, stream>>>(
      fuse_w + 512, 1024, ssmT, 512, wcmb + 524288, 1024, 512, 1024, 512, nullptr, 0);

  mfma_nt<<<dim3(19, 128), 256, 0, stream>>>(
      xb, 512, wb, 512, zx, D_PROJC, D_PROJC, 512, nullptr, 0);

  for (int dir = 0; dir < 2; ++dir) {
    conv_k<<<dim3(5, M_ROWS), 256, 0, stream>>>(zx, conv_w, conv_b, xBC, dir);
    states_mfma_k<<<512, 256, 0, stream>>>(zx, xBC, dt_bias, A_log, acum, dtg, states, dir);
    scan_k<<<256, 256, 0, stream>>>(states, acum);
    y_mfma_k<<<512, 256, 0, stream>>>(xBC, states, acum, dtg, D_skip, ybuf, dir);
    norm_k<<<M_ROWS, 256, 0, stream>>>(ybuf, zx, norm_w);
    mfma_nt<<<dim3(4, 128), 256, 0, stream>>>(
        ybuf, 1024, wcmb + (size_t)dir * 524288, 1024, out, 512,
        512, 1024, dir == 0 ? fuse_b : nullptr, dir == 0 ? 1 : 2);
  }
}

// Round 5
// 706.230 us; speedup vs baseline: 3.1590x; 1.1980x over previous
//
#include <hip/hip_runtime.h>
#include <cstddef>

// Problem constants
#define B_SZ     2
#define L_SEQ    8192
#define D_INNERC 1024
#define NHEADSC  16
#define CHUNKC   64
#define NCHUNKC  128          // L_SEQ / CHUNK
#define CONV_DIMC 1280
#define D_PROJC  2320
#define M_ROWS   16384        // B_SZ * L_SEQ

typedef unsigned short bfu;   // raw bf16 bits

using bf16x8 = __attribute__((ext_vector_type(8))) short;
using f32x4  = __attribute__((ext_vector_type(4))) float;

__device__ __forceinline__ float silu_(float v) { return v / (1.f + expf(-v)); }

__device__ __forceinline__ float b2f(bfu u) {
  return __uint_as_float((unsigned)u << 16);
}
__device__ __forceinline__ bfu f2b(float f) {
  unsigned x = __float_as_uint(f);
  return (bfu)((x + 0x7fffu + ((x >> 16) & 1u)) >> 16);   // RNE
}

__device__ __forceinline__ float4 ld4(const float* p) { return *(const float4*)p; }
__device__ __forceinline__ float4 ld4(const bfu* p) {
  ushort4 u = *(const ushort4*)p;
  float4 f;
  f.x = b2f(u.x); f.y = b2f(u.y); f.z = b2f(u.z); f.w = b2f(u.w);
  return f;
}
__device__ __forceinline__ void st4(float* p, float4 v) { *(float4*)p = v; }
__device__ __forceinline__ void st4(bfu* p, float4 v) {
  ushort4 u;
  u.x = f2b(v.x); u.y = f2b(v.y); u.z = f2b(v.z); u.w = f2b(v.w);
  *(ushort4*)p = u;
}
__device__ __forceinline__ float ld1(const float* p) { return *p; }
__device__ __forceinline__ float ld1(const bfu* p) { return b2f(*p); }
__device__ __forceinline__ void st1(float* p, float v) { *p = v; }
__device__ __forceinline__ void st1(bfu* p, float v) { *p = f2b(v); }

__device__ __forceinline__ void gl_lds16(const bfu* g, bfu* l) {
  __builtin_amdgcn_global_load_lds(
      (const __attribute__((address_space(1))) unsigned int*)g,
      (__attribute__((address_space(3))) unsigned int*)l, 16, 0, 0);
}

__device__ __forceinline__ int pos_of(int b, int c, int l, int dir) {
  int t = c * CHUNKC + l;
  return dir ? (b * L_SEQ + (L_SEQ - 1) - t) : (b * L_SEQ + t);
}

// ---------------------------------------------------------------------------
// MFMA GEMM (NT): C[m][n] = sum_k A[m][k] * Bw[n][k].  A,B bf16, K-contig.
// 128x128 tile, BK=32.  XCD-aware swizzle: all N-tiles of an m-tile map to
// one XCD (blocks dispatch round-robin over 8 XCDs), so A tiles enter each
// XCD L2 exactly once.  Requires gridDim.y % 8 == 0.
// mode: 0 -> store bf16;  1 -> store f32 (+bias);  2 -> f32 +=
// ---------------------------------------------------------------------------
__global__ __launch_bounds__(256)
void mfma_nt(const bfu* __restrict__ A, int lda,
             const bfu* __restrict__ Bw, int ldb,
             void* __restrict__ Cv, int ldc,
             int N, int K, const float* __restrict__ bias, int mode)
{
  __shared__ bfu As[128 * 32];
  __shared__ bfu Bs[128 * 32];
  const int tid  = threadIdx.x;
  const int lane = tid & 63;
  const int wave = __builtin_amdgcn_readfirstlane(tid >> 6);
  const int wm = wave & 1, wn = wave >> 1;

  const int num_n = gridDim.x;
  const int flat  = blockIdx.y * num_n + blockIdx.x;
  const int xcd   = flat & 7;
  const int g     = flat >> 3;
  const int n0 = (g % num_n) * 128;
  const int m0 = ((g / num_n) * 8 + xcd) * 128;

  f32x4 acc[4][4];
#pragma unroll
  for (int i = 0; i < 4; ++i)
#pragma unroll
    for (int j = 0; j < 4; ++j)
      acc[i][j] = (f32x4){0.f, 0.f, 0.f, 0.f};

  const int srow = lane >> 2;
  const int scgp = lane & 3;

  for (int k0 = 0; k0 < K; k0 += 32) {
    __syncthreads();
#pragma unroll
    for (int si = 0; si < 2; ++si) {
      int s = wave * 2 + si;
      int r = s * 16 + srow;
      int cg = scgp ^ ((r >> 1) & 3);
      gl_lds16(A  + (size_t)(m0 + r) * lda + k0 + cg * 8, As + s * 512);
      gl_lds16(Bw + (size_t)(n0 + r) * ldb + k0 + cg * 8, Bs + s * 512);
    }
    __syncthreads();

    bf16x8 af[4], bfr[4];
#pragma unroll
    for (int i = 0; i < 4; ++i) {
      int ra = wm * 64 + i * 16 + (lane & 15);
      int ca = (lane >> 4) ^ ((ra >> 1) & 3);
      af[i] = *(const bf16x8*)(As + ra * 32 + ca * 8);
      int rb = wn * 64 + i * 16 + (lane & 15);
      int cb = (lane >> 4) ^ ((rb >> 1) & 3);
      bfr[i] = *(const bf16x8*)(Bs + rb * 32 + cb * 8);
    }
#pragma unroll
    for (int i = 0; i < 4; ++i)
#pragma unroll
      for (int j = 0; j < 4; ++j)
        acc[i][j] = __builtin_amdgcn_mfma_f32_16x16x32_bf16(af[i], bfr[j], acc[i][j], 0, 0, 0);
  }

  // C/D layout: col = lane&15, row = (lane>>4)*4 + reg
#pragma unroll
  for (int i = 0; i < 4; ++i) {
    int mbase = m0 + wm * 64 + i * 16 + (lane >> 4) * 4;
#pragma unroll
    for (int j = 0; j < 4; ++j) {
      int n = n0 + wn * 64 + j * 16 + (lane & 15);
      if (n < N) {
#pragma unroll
        for (int r = 0; r < 4; ++r) {
          float v = acc[i][j][r];
          size_t off = (size_t)(mbase + r) * ldc + n;
          if (mode == 0) {
            ((bfu*)Cv)[off] = f2b(v);
          } else {
            float* cp = (float*)Cv + off;
            if (mode == 2) v += *cp;
            else if (bias) v += bias[n];
            *cp = v;
          }
        }
      }
    }
  }
}

// ---------------------------------------------------------------------------
// fp32 vector GEMM (NT) — tiny setup GEMMs only.
// ---------------------------------------------------------------------------
template <typename TA, typename TB, typename TC>
__global__ __launch_bounds__(256)
void gemm_nt(const TA* __restrict__ A, int lda,
             const TB* __restrict__ Bw, int ldb,
             TC* __restrict__ C, int ldc,
             int M, int N, int K,
             const float* __restrict__ bias, int accum)
{
  __shared__ float As[16][132];
  __shared__ float Bs[16][132];
  const int tid = threadIdx.x;
  const int n0 = blockIdx.x * 128;
  const int m0 = blockIdx.y * 128;
  const int tx = tid & 15, ty = tid >> 4;
  float acc[8][8] = {};

  for (int k0 = 0; k0 < K; k0 += 16) {
#pragma unroll
    for (int r = 0; r < 2; ++r) {
      int q = tid + r * 256;
      int row = q >> 2, cc = (q & 3) << 2;
      float4 va = ld4(A + (size_t)(m0 + row) * lda + k0 + cc);
      As[cc + 0][row] = va.x; As[cc + 1][row] = va.y;
      As[cc + 2][row] = va.z; As[cc + 3][row] = va.w;
      float4 vb = {0.f, 0.f, 0.f, 0.f};
      if (n0 + row < N)
        vb = ld4(Bw + (size_t)(n0 + row) * ldb + k0 + cc);
      Bs[cc + 0][row] = vb.x; Bs[cc + 1][row] = vb.y;
      Bs[cc + 2][row] = vb.z; Bs[cc + 3][row] = vb.w;
    }
    __syncthreads();
#pragma unroll
    for (int kk = 0; kk < 16; ++kk) {
      float a[8], b[8];
      *(float4*)(a)     = *(float4*)&As[kk][ty * 8];
      *(float4*)(a + 4) = *(float4*)&As[kk][ty * 8 + 4];
      *(float4*)(b)     = *(float4*)&Bs[kk][tx * 8];
      *(float4*)(b + 4) = *(float4*)&Bs[kk][tx * 8 + 4];
#pragma unroll
      for (int i = 0; i < 8; ++i)
#pragma unroll
        for (int j = 0; j < 8; ++j)
          acc[i][j] += a[i] * b[j];
    }
    __syncthreads();
  }

  const bool full = (n0 + 128 <= N);
#pragma unroll
  for (int i = 0; i < 8; ++i) {
    int m = m0 + ty * 8 + i;
    TC* crow = C + (size_t)m * ldc;
    int n = n0 + tx * 8;
    if (full) {
      float4 v0, v1;
      v0.x = acc[i][0]; v0.y = acc[i][1]; v0.z = acc[i][2]; v0.w = acc[i][3];
      v1.x = acc[i][4]; v1.y = acc[i][5]; v1.z = acc[i][6]; v1.w = acc[i][7];
      if (accum) {
        float4 o0 = ld4(crow + n), o1 = ld4(crow + n + 4);
        v0.x += o0.x; v0.y += o0.y; v0.z += o0.z; v0.w += o0.w;
        v1.x += o1.x; v1.y += o1.y; v1.z += o1.z; v1.w += o1.w;
      } else if (bias) {
        v0.x += bias[n + 0]; v0.y += bias[n + 1]; v0.z += bias[n + 2]; v0.w += bias[n + 3];
        v1.x += bias[n + 4]; v1.y += bias[n + 5]; v1.z += bias[n + 6]; v1.w += bias[n + 7];
      }
      st4(crow + n, v0);
      st4(crow + n + 4, v1);
    } else {
#pragma unroll
      for (int j = 0; j < 8; ++j) {
        int nn = n + j;
        if (nn < N) {
          float v = acc[i][j];
          if (accum) v += ld1(crow + nn);
          else if (bias) v += bias[nn];
          st1(crow + nn, v);
        }
      }
    }
  }
}

// ---------------------------------------------------------------------------
// fp32 -> bf16 converts + transpose (setup)
// ---------------------------------------------------------------------------
__global__ __launch_bounds__(256)
void cvt_x_k(const float* __restrict__ in, bfu* __restrict__ out)
{
  int q = blockIdx.x * 256 + threadIdx.x;
  st4(out + (size_t)q * 4, ld4(in + (size_t)q * 4));
}

__global__ __launch_bounds__(256)
void cvt_w_k(const float* __restrict__ in, bfu* __restrict__ out)
{
  int q = blockIdx.x * 256 + threadIdx.x;
  int row = q >> 7, c4 = (q & 127) << 2;
  float4 v = {0.f, 0.f, 0.f, 0.f};
  if (row < D_PROJC) v = ld4(in + (size_t)row * 512 + c4);
  st4(out + (size_t)row * 512 + c4, v);
}

__global__ __launch_bounds__(256)
void transpose_k(const float* __restrict__ in, float* __restrict__ out)
{
  int idx = blockIdx.x * 256 + threadIdx.x;
  int j = idx >> 9, k = idx & 511;
  out[idx] = in[k * 1024 + j];
}

// ---------------------------------------------------------------------------
// Depthwise conv + bias + SiLU, 8 outputs per thread (taps staged in regs).
// grid (5, 2048): block = 256 channels x 8 time steps.
// ---------------------------------------------------------------------------
__global__ __launch_bounds__(256)
void conv_k(const bfu* __restrict__ zx, const float* __restrict__ conv_w,
            const float* __restrict__ conv_b, bfu* __restrict__ xBC, int dir)
{
  int ch = blockIdx.x * 256 + threadIdx.x;   // 0..1279
  int m0 = blockIdx.y * 8;                   // global row base
  int b  = m0 >> 13, tb = m0 & (L_SEQ - 1);
  float w0 = conv_w[ch * 4 + 0], w1 = conv_w[ch * 4 + 1];
  float w2 = conv_w[ch * 4 + 2], w3 = conv_w[ch * 4 + 3];
  float cb = conv_b[ch];
  const bfu* src = zx + 1024 + ch;
  const int shift = dir ? 0 : 3;

  float v[11];
#pragma unroll
  for (int i = 0; i < 11; ++i) {
    int tt = tb + i - shift;
    v[i] = (tt >= 0 && tt < L_SEQ)
         ? b2f(src[(size_t)(b * L_SEQ + tt) * D_PROJC]) : 0.f;
  }
#pragma unroll
  for (int j = 0; j < 8; ++j) {
    float acc = cb;
    if (dir == 0) {
      acc += w0 * v[j] + w1 * v[j + 1] + w2 * v[j + 2] + w3 * v[j + 3];
    } else {
      acc += w0 * v[j + 3] + w1 * v[j + 2] + w2 * v[j + 1] + w3 * v[j];
    }
    xBC[(size_t)(m0 + j) * CONV_DIMC + ch] = f2b(silu_(acc));
  }
}

// ---------------------------------------------------------------------------
// MFMA states: per (b,c) block, 8 heads/block (grid 512/dir).
// ---------------------------------------------------------------------------
__global__ __launch_bounds__(256)
void states_mfma_k(const bfu* __restrict__ zx, const bfu* __restrict__ xBC,
                   const float* __restrict__ dt_bias, const float* __restrict__ A_log,
                   float* __restrict__ acum_g, float* __restrict__ dt_g,
                   bfu* __restrict__ states, int dir)
{
  __shared__ bfu BT[128 * 72];     // [n][l]
  __shared__ bfu xsT[64 * 72];     // [p][l]
  __shared__ float scaleS[8 * 64];

  int bid = blockIdx.x;
  int hb = bid >> 8;
  int c = bid & 127, b = (bid >> 7) & 1;
  int tid = threadIdx.x, lane = tid & 63;
  int w = tid >> 6, q = lane >> 4, t = lane & 15;

#pragma unroll
  for (int rr = 0; rr < 2; ++rr) {
    int i = w + rr * 4;
    int h = hb * 8 + i;
    int l = lane;
    int pos = pos_of(b, c, l, dir);
    float dtr = b2f(zx[(size_t)pos * D_PROJC + 2304 + h]) + dt_bias[h];
    float dt = (dtr > 20.f) ? dtr : log1pf(expf(dtr));
    float a = -expf(A_log[h]) * dt;
#pragma unroll
    for (int off = 1; off < 64; off <<= 1) {
      float v = __shfl_up(a, off);
      if (l >= off) a += v;
    }
    float alast = __shfl(a, 63);
    int gi = ((b * NCHUNKC + c) * NHEADSC + h) * 64 + l;
    acum_g[gi] = a; dt_g[gi] = dt;
    scaleS[i * 64 + l] = dt * expf(alast - a);
  }

#pragma unroll
  for (int r = 0; r < 8; ++r) {
    int qq = tid + r * 256;
    int l = qq & 63, ng = qq >> 6;
    ushort4 v = *(const ushort4*)(xBC + (size_t)pos_of(b, c, l, dir) * CONV_DIMC + 1024 + ng * 4);
    BT[(ng * 4 + 0) * 72 + l] = v.x; BT[(ng * 4 + 1) * 72 + l] = v.y;
    BT[(ng * 4 + 2) * 72 + l] = v.z; BT[(ng * 4 + 3) * 72 + l] = v.w;
  }
  __syncthreads();

  for (int i = 0; i < 8; ++i) {
    int h = hb * 8 + i;
#pragma unroll
    for (int r = 0; r < 4; ++r) {
      int qq = tid + r * 256;
      int l = qq & 63, pg = qq >> 6;
      float s = scaleS[i * 64 + l];
      ushort4 v = *(const ushort4*)(xBC + (size_t)pos_of(b, c, l, dir) * CONV_DIMC + h * 64 + pg * 4);
      xsT[(pg * 4 + 0) * 72 + l] = f2b(b2f(v.x) * s);
      xsT[(pg * 4 + 1) * 72 + l] = f2b(b2f(v.y) * s);
      xsT[(pg * 4 + 2) * 72 + l] = f2b(b2f(v.z) * s);
      xsT[(pg * 4 + 3) * 72 + l] = f2b(b2f(v.w) * s);
    }
    __syncthreads();

    bf16x8 axs[2];
#pragma unroll
    for (int ks = 0; ks < 2; ++ks)
      axs[ks] = *(const bf16x8*)(xsT + (w * 16 + t) * 72 + ks * 32 + q * 8);

    f32x4 acc[8];
#pragma unroll
    for (int j = 0; j < 8; ++j) acc[j] = (f32x4){0.f, 0.f, 0.f, 0.f};
#pragma unroll
    for (int ks = 0; ks < 2; ++ks)
#pragma unroll
      for (int j = 0; j < 8; ++j) {
        bf16x8 bB = *(const bf16x8*)(BT + (j * 16 + t) * 72 + ks * 32 + q * 8);
        acc[j] = __builtin_amdgcn_mfma_f32_16x16x32_bf16(axs[ks], bB, acc[j], 0, 0, 0);
      }

    size_t base = ((size_t)(b * NCHUNKC + c) * NHEADSC + h) * 8192;
#pragma unroll
    for (int j = 0; j < 8; ++j)
#pragma unroll
      for (int r = 0; r < 4; ++r) {
        int p = w * 16 + q * 4 + r, n = j * 16 + t;
        states[base + p * 128 + n] = f2b(acc[j][r]);
      }
    __syncthreads();
  }
}

// ---------------------------------------------------------------------------
// Inter-chunk scan with explicit next-chunk prefetch.  512 blocks: (b,h,eb),
// each thread owns 2 consecutive state elements (ushort2).
// ---------------------------------------------------------------------------
__global__ __launch_bounds__(256)
void scan_k(bfu* __restrict__ states, const float* __restrict__ acum_g)
{
  int bid = blockIdx.x;
  int eb = bid & 15, h = (bid >> 4) & 15, b = bid >> 8;
  int e = eb * 512 + threadIdx.x * 2;
  bfu* p0 = states + ((size_t)(b * NCHUNKC) * NHEADSC + h) * 8192 + e;
  const float* ac = acum_g + ((b * NCHUNKC) * NHEADSC + h) * 64 + 63;
  const size_t cstride = (size_t)NHEADSC * 8192;   // elems per chunk step
  const int astride = NHEADSC * 64;

  float pre0 = 0.f, pre1 = 0.f;
  uint raw = *(const uint*)p0;
  float dcur = expf(ac[0]);
  for (int c = 0; c < NCHUNKC; ++c) {
    uint raw_next = 0; float dnext = 0.f;
    if (c < NCHUNKC - 1) {
      raw_next = *(const uint*)(p0 + (c + 1) * cstride);
      dnext = expf(ac[(c + 1) * astride]);
    }
    float v0 = b2f((bfu)(raw & 0xffff));
    float v1 = b2f((bfu)(raw >> 16));
    uint packed = (uint)f2b(pre0) | ((uint)f2b(pre1) << 16);
    *(uint*)(p0 + c * cstride) = packed;
    pre0 = v0 + dcur * pre0;
    pre1 = v1 + dcur * pre1;
    raw = raw_next; dcur = dnext;
  }
}

// ---------------------------------------------------------------------------
// MFMA Y: per (b,c) block, 8 heads/block (grid 512/dir).
// ---------------------------------------------------------------------------
__global__ __launch_bounds__(256)
void y_mfma_k(const bfu* __restrict__ xBC, const bfu* __restrict__ states,
              const float* __restrict__ acum_g, const float* __restrict__ dt_g,
              const float* __restrict__ D_skip, bfu* __restrict__ ybuf, int dir)
{
  __shared__ bfu smem[30976];
  bfu* Cs  = smem;                      // 64 x 136
  bfu* Bsc = smem + 8704;               // 64 x 136 (B tile; sc overlays)
  bfu* Ps  = smem + 17408;              // 64 x 136
  bfu* xhT = smem + 26112;              // 64 x 72
  float* acumH = (float*)(smem + 30720);
  float* dtH   = acumH + 64;

  int bid = blockIdx.x;
  int hb = bid >> 8;
  int c = bid & 127, b = (bid >> 7) & 1;
  int tid = threadIdx.x, lane = tid & 63;
  int w = tid >> 6, q = lane >> 4, t = lane & 15;

#pragma unroll
  for (int r = 0; r < 8; ++r) {
    int qq = tid + r * 256;
    int row = qq >> 5, grp = qq & 31;
    const bfu* src = xBC + (size_t)pos_of(b, c, row, dir) * CONV_DIMC;
    *(ushort4*)(Cs  + row * 136 + grp * 4) = *(const ushort4*)(src + 1152 + grp * 4);
    *(ushort4*)(Bsc + row * 136 + grp * 4) = *(const ushort4*)(src + 1024 + grp * 4);
  }
  __syncthreads();

  bf16x8 af[4];
#pragma unroll
  for (int ks = 0; ks < 4; ++ks)
    af[ks] = *(const bf16x8*)(Cs + (w * 16 + t) * 136 + ks * 32 + q * 8);

  f32x4 sacc[4];
#pragma unroll
  for (int j = 0; j < 4; ++j) sacc[j] = (f32x4){0.f, 0.f, 0.f, 0.f};
#pragma unroll
  for (int ks = 0; ks < 4; ++ks)
#pragma unroll
    for (int j = 0; j < 4; ++j) {
      bf16x8 bf = *(const bf16x8*)(Bsc + (j * 16 + t) * 136 + ks * 32 + q * 8);
      sacc[j] = __builtin_amdgcn_mfma_f32_16x16x32_bf16(af[ks], bf, sacc[j], 0, 0, 0);
    }

  for (int i = 0; i < 8; ++i) {
    int h = hb * 8 + i;
    __syncthreads();
    size_t pbase = ((size_t)(b * NCHUNKC + c) * NHEADSC + h) * 8192;
#pragma unroll
    for (int r = 0; r < 8; ++r) {
      int qq = tid + r * 256;
      int row = qq >> 5, grp = qq & 31;
      *(ushort4*)(Ps + row * 136 + grp * 4) =
          *(const ushort4*)(states + pbase + row * 128 + grp * 4);
    }
#pragma unroll
    for (int r = 0; r < 4; ++r) {
      int qq = tid + r * 256;
      int l = qq & 63, pg = qq >> 6;
      ushort4 v = *(const ushort4*)(xBC + (size_t)pos_of(b, c, l, dir) * CONV_DIMC + h * 64 + pg * 4);
      xhT[(pg * 4 + 0) * 72 + l] = v.x; xhT[(pg * 4 + 1) * 72 + l] = v.y;
      xhT[(pg * 4 + 2) * 72 + l] = v.z; xhT[(pg * 4 + 3) * 72 + l] = v.w;
    }
    if (tid < 64) {
      int gi = ((b * NCHUNKC + c) * NHEADSC + h) * 64 + tid;
      acumH[tid] = acum_g[gi]; dtH[tid] = dt_g[gi];
    }
    __syncthreads();

    f32x4 yacc[4];
#pragma unroll
    for (int j = 0; j < 4; ++j) yacc[j] = (f32x4){0.f, 0.f, 0.f, 0.f};
#pragma unroll
    for (int ks = 0; ks < 4; ++ks)
#pragma unroll
      for (int j = 0; j < 4; ++j) {
        bf16x8 bP = *(const bf16x8*)(Ps + (j * 16 + t) * 136 + ks * 32 + q * 8);
        yacc[j] = __builtin_amdgcn_mfma_f32_16x16x32_bf16(af[ks], bP, yacc[j], 0, 0, 0);
      }

    float Dh = D_skip[h];
    bfu* sc = Bsc;
#pragma unroll
    for (int j = 0; j < 4; ++j)
#pragma unroll
      for (int r = 0; r < 4; ++r) {
        int l = w * 16 + q * 4 + r, s = j * 16 + t;
        float v = 0.f;
        if (s <= l) v = sacc[j][r] * expf(acumH[l] - acumH[s]) * dtH[s];
        if (s == l) v += Dh;
        sc[l * 72 + s] = f2b(v);
      }

    f32x4 acc2[4];
    float dec[4];
#pragma unroll
    for (int r = 0; r < 4; ++r) dec[r] = expf(acumH[w * 16 + q * 4 + r]);
#pragma unroll
    for (int j = 0; j < 4; ++j)
#pragma unroll
      for (int r = 0; r < 4; ++r) acc2[j][r] = yacc[j][r] * dec[r];

#pragma unroll
    for (int ks = 0; ks < 2; ++ks) {
      bf16x8 asc = *(const bf16x8*)(sc + (w * 16 + t) * 72 + ks * 32 + q * 8);
#pragma unroll
      for (int j = 0; j < 4; ++j) {
        bf16x8 bx = *(const bf16x8*)(xhT + (j * 16 + t) * 72 + ks * 32 + q * 8);
        acc2[j] = __builtin_amdgcn_mfma_f32_16x16x32_bf16(asc, bx, acc2[j], 0, 0, 0);
      }
    }

#pragma unroll
    for (int j = 0; j < 4; ++j)
#pragma unroll
      for (int r = 0; r < 4; ++r) {
        int l = w * 16 + q * 4 + r, p = j * 16 + t;
        ybuf[(size_t)pos_of(b, c, l, dir) * D_INNERC + h * 64 + p] = f2b(acc2[j][r]);
      }
  }
}

// ---------------------------------------------------------------------------
// Gating (y *= silu(z)) + RMSNorm over 1024 + norm_w, in place on ybuf (bf16)
// ---------------------------------------------------------------------------
__global__ __launch_bounds__(256)
void norm_k(bfu* __restrict__ ybuf, const bfu* __restrict__ zx,
            const float* __restrict__ norm_w)
{
  int m = blockIdx.x, tid = threadIdx.x;
  float4 y = ld4(ybuf + (size_t)m * D_INNERC + tid * 4);
  float4 z = ld4(zx + (size_t)m * D_PROJC + tid * 4);
  float4 g;
  g.x = y.x * silu_(z.x); g.y = y.y * silu_(z.y);
  g.z = y.z * silu_(z.z); g.w = y.w * silu_(z.w);
  float ss = g.x * g.x + g.y * g.y + g.z * g.z + g.w * g.w;
#pragma unroll
  for (int off = 32; off >= 1; off >>= 1) ss += __shfl_xor(ss, off);
  __shared__ float red[4];
  int wid = tid >> 6;
  if ((tid & 63) == 0) red[wid] = ss;
  __syncthreads();
  float tot = red[0] + red[1] + red[2] + red[3];
  float scale = rsqrtf(tot * (1.f / 1024.f) + 1e-5f);
  float4 w = *(const float4*)(norm_w + tid * 4);
  g.x *= scale * w.x; g.y *= scale * w.y; g.z *= scale * w.z; g.w *= scale * w.w;
  st4(ybuf + (size_t)m * D_INNERC + tid * 4, g);
}

// ---------------------------------------------------------------------------
extern "C" void kernel_launch(void* const* d_in, const int* in_sizes, int n_in,
                              void* d_out, int out_size, void* d_ws, size_t ws_size,
                              hipStream_t stream)
{
  const float* x         = (const float*)d_in[0];
  const float* in_proj_w = (const float*)d_in[1];
  const float* conv_w    = (const float*)d_in[2];
  const float* conv_b    = (const float*)d_in[3];
  const float* dt_bias   = (const float*)d_in[4];
  const float* A_log     = (const float*)d_in[5];
  const float* D_skip    = (const float*)d_in[6];
  const float* norm_w    = (const float*)d_in[7];
  const float* ssm_out_w = (const float*)d_in[8];
  const float* fuse_w    = (const float*)d_in[9];
  const float* fuse_b    = (const float*)d_in[10];
  float* out = (float*)d_out;

  // workspace layout — ~225 MB
  bfu* zx     = (bfu*)d_ws;                          // 16384 x 2320 bf16
  bfu* xBC    = zx     + (size_t)M_ROWS * D_PROJC;   // 16384 x 1280 bf16
  bfu* states = xBC    + (size_t)M_ROWS * CONV_DIMC; // 33,554,432 bf16
  bfu* ybuf   = states + (size_t)33554432;           // 16384 x 1024 bf16
  float* acum = (float*)(ybuf + (size_t)M_ROWS * D_INNERC); // 262144 f32
  float* dtg  = acum + 262144;                       // 262144 f32
  float* ssmT = dtg  + 262144;                       // 1024 x 512 f32
  bfu* wcmb   = (bfu*)(ssmT + 524288);               // 2 x 512 x 1024 bf16
  // transient aliases inside the states region (dead before states_mfma_k):
  bfu* xb = states;                    // 16384 x 512 bf16
  bfu* wb = states + 8388608;          // 2432  x 512 bf16

  cvt_x_k<<<8192, 256, 0, stream>>>(x, xb);
  cvt_w_k<<<1216, 256, 0, stream>>>(in_proj_w, wb);

  transpose_k<<<2048, 256, 0, stream>>>(ssm_out_w, ssmT);
  gemm_nt<float, float, bfu><<<dim3(8, 4), 256, 0, stream>>>(
      fuse_w, 1024, ssmT, 512, wcmb, 1024, 512, 1024, 512, nullptr, 0);
  gemm_nt<float, float, bfu><<<dim3(8, 4), 256, 0, stream>>>(
      fuse_w + 512, 1024, ssmT, 512, wcmb + 524288, 1024, 512, 1024, 512, nullptr, 0);

  mfma_nt<<<dim3(19, 128), 256, 0, stream>>>(
      xb, 512, wb, 512, zx, D_PROJC, D_PROJC, 512, nullptr, 0);

  for (int dir = 0; dir < 2; ++dir) {
    conv_k<<<dim3(5, 2048), 256, 0, stream>>>(zx, conv_w, conv_b, xBC, dir);
    states_mfma_k<<<512, 256, 0, stream>>>(zx, xBC, dt_bias, A_log, acum, dtg, states, dir);
    scan_k<<<512, 256, 0, stream>>>(states, acum);
    y_mfma_k<<<512, 256, 0, stream>>>(xBC, states, acum, dtg, D_skip, ybuf, dir);
    norm_k<<<M_ROWS, 256, 0, stream>>>(ybuf, zx, norm_w);
    mfma_nt<<<dim3(4, 128), 256, 0, stream>>>(
        ybuf, 1024, wcmb + (size_t)dir * 524288, 1024, out, 512,
        512, 1024, dir == 0 ? fuse_b : nullptr, dir == 0 ? 1 : 2);
  }
}

// Round 6
// 571.832 us; speedup vs baseline: 3.9014x; 1.2350x over previous
//
#include <hip/hip_runtime.h>
#include <cstddef>

// Problem constants
#define B_SZ     2
#define L_SEQ    8192
#define D_INNERC 1024
#define NHEADSC  16
#define CHUNKC   64
#define NCHUNKC  128          // L_SEQ / CHUNK
#define CONV_DIMC 1280
#define D_PROJC  2320
#define M_ROWS   16384        // B_SZ * L_SEQ

typedef unsigned short bfu;   // raw bf16 bits

using bf16x8 = __attribute__((ext_vector_type(8))) short;
using f32x4  = __attribute__((ext_vector_type(4))) float;

__device__ __forceinline__ float silu_(float v) { return v / (1.f + expf(-v)); }

__device__ __forceinline__ float b2f(bfu u) {
  return __uint_as_float((unsigned)u << 16);
}
__device__ __forceinline__ bfu f2b(float f) {
  unsigned x = __float_as_uint(f);
  return (bfu)((x + 0x7fffu + ((x >> 16) & 1u)) >> 16);   // RNE
}

__device__ __forceinline__ float4 ld4(const float* p) { return *(const float4*)p; }
__device__ __forceinline__ float4 ld4(const bfu* p) {
  ushort4 u = *(const ushort4*)p;
  float4 f;
  f.x = b2f(u.x); f.y = b2f(u.y); f.z = b2f(u.z); f.w = b2f(u.w);
  return f;
}
__device__ __forceinline__ void st4(float* p, float4 v) { *(float4*)p = v; }
__device__ __forceinline__ void st4(bfu* p, float4 v) {
  ushort4 u;
  u.x = f2b(v.x); u.y = f2b(v.y); u.z = f2b(v.z); u.w = f2b(v.w);
  *(ushort4*)p = u;
}

__device__ __forceinline__ void gl_lds16(const bfu* g, bfu* l) {
  __builtin_amdgcn_global_load_lds(
      (const __attribute__((address_space(1))) unsigned int*)g,
      (__attribute__((address_space(3))) unsigned int*)l, 16, 0, 0);
}

__device__ __forceinline__ int pos_of(int b, int c, int l, int dir) {
  int t = c * CHUNKC + l;
  return dir ? (b * L_SEQ + (L_SEQ - 1) - t) : (b * L_SEQ + t);
}

// ---------------------------------------------------------------------------
// MFMA GEMM (NT): C[m][n] = sum_k A[m][k] * Bw[n][k].  A,B bf16, K-contig.
// 128x128 tile, BK=32.  XCD-aware swizzle: all N-tiles of an m-tile map to
// one XCD (blocks dispatch round-robin over 8 XCDs), so A tiles enter each
// XCD L2 exactly once.  Requires gridDim.y % 8 == 0.
// mode: 0 -> store bf16;  1 -> store f32 (+bias);  2 -> f32 +=
// ---------------------------------------------------------------------------
__global__ __launch_bounds__(256)
void mfma_nt(const bfu* __restrict__ A, int lda,
             const bfu* __restrict__ Bw, int ldb,
             void* __restrict__ Cv, int ldc,
             int N, int K, const float* __restrict__ bias, int mode)
{
  __shared__ bfu As[128 * 32];
  __shared__ bfu Bs[128 * 32];
  const int tid  = threadIdx.x;
  const int lane = tid & 63;
  const int wave = __builtin_amdgcn_readfirstlane(tid >> 6);
  const int wm = wave & 1, wn = wave >> 1;

  const int num_n = gridDim.x;
  const int flat  = blockIdx.y * num_n + blockIdx.x;
  const int xcd   = flat & 7;
  const int g     = flat >> 3;
  const int n0 = (g % num_n) * 128;
  const int m0 = ((g / num_n) * 8 + xcd) * 128;

  f32x4 acc[4][4];
#pragma unroll
  for (int i = 0; i < 4; ++i)
#pragma unroll
    for (int j = 0; j < 4; ++j)
      acc[i][j] = (f32x4){0.f, 0.f, 0.f, 0.f};

  const int srow = lane >> 2;
  const int scgp = lane & 3;

  for (int k0 = 0; k0 < K; k0 += 32) {
    __syncthreads();
#pragma unroll
    for (int si = 0; si < 2; ++si) {
      int s = wave * 2 + si;
      int r = s * 16 + srow;
      int cg = scgp ^ ((r >> 1) & 3);
      gl_lds16(A  + (size_t)(m0 + r) * lda + k0 + cg * 8, As + s * 512);
      gl_lds16(Bw + (size_t)(n0 + r) * ldb + k0 + cg * 8, Bs + s * 512);
    }
    __syncthreads();

    bf16x8 af[4], bfr[4];
#pragma unroll
    for (int i = 0; i < 4; ++i) {
      int ra = wm * 64 + i * 16 + (lane & 15);
      int ca = (lane >> 4) ^ ((ra >> 1) & 3);
      af[i] = *(const bf16x8*)(As + ra * 32 + ca * 8);
      int rb = wn * 64 + i * 16 + (lane & 15);
      int cb = (lane >> 4) ^ ((rb >> 1) & 3);
      bfr[i] = *(const bf16x8*)(Bs + rb * 32 + cb * 8);
    }
#pragma unroll
    for (int i = 0; i < 4; ++i)
#pragma unroll
      for (int j = 0; j < 4; ++j)
        acc[i][j] = __builtin_amdgcn_mfma_f32_16x16x32_bf16(af[i], bfr[j], acc[i][j], 0, 0, 0);
  }

  // C/D layout: col = lane&15, row = (lane>>4)*4 + reg
#pragma unroll
  for (int i = 0; i < 4; ++i) {
    int mbase = m0 + wm * 64 + i * 16 + (lane >> 4) * 4;
#pragma unroll
    for (int j = 0; j < 4; ++j) {
      int n = n0 + wn * 64 + j * 16 + (lane & 15);
      if (n < N) {
#pragma unroll
        for (int r = 0; r < 4; ++r) {
          float v = acc[i][j][r];
          size_t off = (size_t)(mbase + r) * ldc + n;
          if (mode == 0) {
            ((bfu*)Cv)[off] = f2b(v);
          } else {
            float* cp = (float*)Cv + off;
            if (mode == 2) v += *cp;
            else if (bias) v += bias[n];
            *cp = v;
          }
        }
      }
    }
  }
}

// ---------------------------------------------------------------------------
// setup converts (all fp32 -> bf16)
// ---------------------------------------------------------------------------
__global__ __launch_bounds__(256)
void cvt_x_k(const float* __restrict__ in, bfu* __restrict__ out)
{
  int q = blockIdx.x * 256 + threadIdx.x;
  st4(out + (size_t)q * 4, ld4(in + (size_t)q * 4));
}

__global__ __launch_bounds__(256)
void cvt_w_k(const float* __restrict__ in, bfu* __restrict__ out)
{
  int q = blockIdx.x * 256 + threadIdx.x;
  int row = q >> 7, c4 = (q & 127) << 2;
  float4 v = {0.f, 0.f, 0.f, 0.f};
  if (row < D_PROJC) v = ld4(in + (size_t)row * 512 + c4);
  st4(out + (size_t)row * 512 + c4, v);
}

// ssm_out_w (512 x 1024 f32) -> ssmTb (1024 x 512 bf16)
__global__ __launch_bounds__(256)
void transpose_k(const float* __restrict__ in, bfu* __restrict__ out)
{
  int idx = blockIdx.x * 256 + threadIdx.x;   // 0 .. 524287
  int j = idx >> 9, k = idx & 511;
  out[idx] = f2b(in[k * 1024 + j]);
}

// fuse_w (512 x 1024 f32) -> fuseA (1024 x 512 bf16), row m = dir*512 + o
__global__ __launch_bounds__(256)
void cvt_fuse_k(const float* __restrict__ in, bfu* __restrict__ out)
{
  int q = blockIdx.x * 256 + threadIdx.x;     // 0 .. 131071 (4-elem groups)
  int m = q >> 7, kg = (q & 127) << 2;
  float4 v = ld4(in + (size_t)(m & 511) * 1024 + (m >> 9) * 512 + kg);
  st4(out + (size_t)m * 512 + kg, v);
}

// ---------------------------------------------------------------------------
// Depthwise conv + bias + SiLU, 8 outputs per thread (taps staged in regs).
// ---------------------------------------------------------------------------
__global__ __launch_bounds__(256)
void conv_k(const bfu* __restrict__ zx, const float* __restrict__ conv_w,
            const float* __restrict__ conv_b, bfu* __restrict__ xBC, int dir)
{
  int ch = blockIdx.x * 256 + threadIdx.x;   // 0..1279
  int m0 = blockIdx.y * 8;                   // global row base
  int b  = m0 >> 13, tb = m0 & (L_SEQ - 1);
  float w0 = conv_w[ch * 4 + 0], w1 = conv_w[ch * 4 + 1];
  float w2 = conv_w[ch * 4 + 2], w3 = conv_w[ch * 4 + 3];
  float cb = conv_b[ch];
  const bfu* src = zx + 1024 + ch;
  const int shift = dir ? 0 : 3;

  float v[11];
#pragma unroll
  for (int i = 0; i < 11; ++i) {
    int tt = tb + i - shift;
    v[i] = (tt >= 0 && tt < L_SEQ)
         ? b2f(src[(size_t)(b * L_SEQ + tt) * D_PROJC]) : 0.f;
  }
#pragma unroll
  for (int j = 0; j < 8; ++j) {
    float acc = cb;
    if (dir == 0) {
      acc += w0 * v[j] + w1 * v[j + 1] + w2 * v[j + 2] + w3 * v[j + 3];
    } else {
      acc += w0 * v[j + 3] + w1 * v[j + 2] + w2 * v[j + 1] + w3 * v[j];
    }
    xBC[(size_t)(m0 + j) * CONV_DIMC + ch] = f2b(silu_(acc));
  }
}

// ---------------------------------------------------------------------------
// MFMA states: per (b,c) block, 8 heads/block (grid 512/dir).
// ---------------------------------------------------------------------------
__global__ __launch_bounds__(256)
void states_mfma_k(const bfu* __restrict__ zx, const bfu* __restrict__ xBC,
                   const float* __restrict__ dt_bias, const float* __restrict__ A_log,
                   float* __restrict__ acum_g, float* __restrict__ dt_g,
                   bfu* __restrict__ states, int dir)
{
  __shared__ bfu BT[128 * 72];     // [n][l]
  __shared__ bfu xsT[64 * 72];     // [p][l]
  __shared__ float scaleS[8 * 64];

  int bid = blockIdx.x;
  int hb = bid >> 8;
  int c = bid & 127, b = (bid >> 7) & 1;
  int tid = threadIdx.x, lane = tid & 63;
  int w = tid >> 6, q = lane >> 4, t = lane & 15;

#pragma unroll
  for (int rr = 0; rr < 2; ++rr) {
    int i = w + rr * 4;
    int h = hb * 8 + i;
    int l = lane;
    int pos = pos_of(b, c, l, dir);
    float dtr = b2f(zx[(size_t)pos * D_PROJC + 2304 + h]) + dt_bias[h];
    float dt = (dtr > 20.f) ? dtr : log1pf(expf(dtr));
    float a = -expf(A_log[h]) * dt;
#pragma unroll
    for (int off = 1; off < 64; off <<= 1) {
      float v = __shfl_up(a, off);
      if (l >= off) a += v;
    }
    float alast = __shfl(a, 63);
    int gi = ((b * NCHUNKC + c) * NHEADSC + h) * 64 + l;
    acum_g[gi] = a; dt_g[gi] = dt;
    scaleS[i * 64 + l] = dt * expf(alast - a);
  }

#pragma unroll
  for (int r = 0; r < 8; ++r) {
    int qq = tid + r * 256;
    int l = qq & 63, ng = qq >> 6;
    ushort4 v = *(const ushort4*)(xBC + (size_t)pos_of(b, c, l, dir) * CONV_DIMC + 1024 + ng * 4);
    BT[(ng * 4 + 0) * 72 + l] = v.x; BT[(ng * 4 + 1) * 72 + l] = v.y;
    BT[(ng * 4 + 2) * 72 + l] = v.z; BT[(ng * 4 + 3) * 72 + l] = v.w;
  }
  __syncthreads();

  for (int i = 0; i < 8; ++i) {
    int h = hb * 8 + i;
#pragma unroll
    for (int r = 0; r < 4; ++r) {
      int qq = tid + r * 256;
      int l = qq & 63, pg = qq >> 6;
      float s = scaleS[i * 64 + l];
      ushort4 v = *(const ushort4*)(xBC + (size_t)pos_of(b, c, l, dir) * CONV_DIMC + h * 64 + pg * 4);
      xsT[(pg * 4 + 0) * 72 + l] = f2b(b2f(v.x) * s);
      xsT[(pg * 4 + 1) * 72 + l] = f2b(b2f(v.y) * s);
      xsT[(pg * 4 + 2) * 72 + l] = f2b(b2f(v.z) * s);
      xsT[(pg * 4 + 3) * 72 + l] = f2b(b2f(v.w) * s);
    }
    __syncthreads();

    bf16x8 axs[2];
#pragma unroll
    for (int ks = 0; ks < 2; ++ks)
      axs[ks] = *(const bf16x8*)(xsT + (w * 16 + t) * 72 + ks * 32 + q * 8);

    f32x4 acc[8];
#pragma unroll
    for (int j = 0; j < 8; ++j) acc[j] = (f32x4){0.f, 0.f, 0.f, 0.f};
#pragma unroll
    for (int ks = 0; ks < 2; ++ks)
#pragma unroll
      for (int j = 0; j < 8; ++j) {
        bf16x8 bB = *(const bf16x8*)(BT + (j * 16 + t) * 72 + ks * 32 + q * 8);
        acc[j] = __builtin_amdgcn_mfma_f32_16x16x32_bf16(axs[ks], bB, acc[j], 0, 0, 0);
      }

    size_t base = ((size_t)(b * NCHUNKC + c) * NHEADSC + h) * 8192;
#pragma unroll
    for (int j = 0; j < 8; ++j)
#pragma unroll
      for (int r = 0; r < 4; ++r) {
        int p = w * 16 + q * 4 + r, n = j * 16 + t;
        states[base + p * 128 + n] = f2b(acc[j][r]);
      }
    __syncthreads();
  }
}

// ---------------------------------------------------------------------------
// Inter-chunk scan with explicit next-chunk prefetch.  512 blocks: (b,h,eb)
// ---------------------------------------------------------------------------
__global__ __launch_bounds__(256)
void scan_k(bfu* __restrict__ states, const float* __restrict__ acum_g)
{
  int bid = blockIdx.x;
  int eb = bid & 15, h = (bid >> 4) & 15, b = bid >> 8;
  int e = eb * 512 + threadIdx.x * 2;
  bfu* p0 = states + ((size_t)(b * NCHUNKC) * NHEADSC + h) * 8192 + e;
  const float* ac = acum_g + ((b * NCHUNKC) * NHEADSC + h) * 64 + 63;
  const size_t cstride = (size_t)NHEADSC * 8192;
  const int astride = NHEADSC * 64;

  float pre0 = 0.f, pre1 = 0.f;
  uint raw = *(const uint*)p0;
  float dcur = expf(ac[0]);
  for (int c = 0; c < NCHUNKC; ++c) {
    uint raw_next = 0; float dnext = 0.f;
    if (c < NCHUNKC - 1) {
      raw_next = *(const uint*)(p0 + (c + 1) * cstride);
      dnext = expf(ac[(c + 1) * astride]);
    }
    float v0 = b2f((bfu)(raw & 0xffff));
    float v1 = b2f((bfu)(raw >> 16));
    uint packed = (uint)f2b(pre0) | ((uint)f2b(pre1) << 16);
    *(uint*)(p0 + c * cstride) = packed;
    pre0 = v0 + dcur * pre0;
    pre1 = v1 + dcur * pre1;
    raw = raw_next; dcur = dnext;
  }
}

// ---------------------------------------------------------------------------
// MFMA Y: per (b,c) block, 8 heads/block (grid 512/dir).
// ---------------------------------------------------------------------------
__global__ __launch_bounds__(256)
void y_mfma_k(const bfu* __restrict__ xBC, const bfu* __restrict__ states,
              const float* __restrict__ acum_g, const float* __restrict__ dt_g,
              const float* __restrict__ D_skip, bfu* __restrict__ ybuf, int dir)
{
  __shared__ bfu smem[30976];
  bfu* Cs  = smem;                      // 64 x 136
  bfu* Bsc = smem + 8704;               // 64 x 136 (B tile; sc overlays)
  bfu* Ps  = smem + 17408;              // 64 x 136
  bfu* xhT = smem + 26112;              // 64 x 72
  float* acumH = (float*)(smem + 30720);
  float* dtH   = acumH + 64;

  int bid = blockIdx.x;
  int hb = bid >> 8;
  int c = bid & 127, b = (bid >> 7) & 1;
  int tid = threadIdx.x, lane = tid & 63;
  int w = tid >> 6, q = lane >> 4, t = lane & 15;

#pragma unroll
  for (int r = 0; r < 8; ++r) {
    int qq = tid + r * 256;
    int row = qq >> 5, grp = qq & 31;
    const bfu* src = xBC + (size_t)pos_of(b, c, row, dir) * CONV_DIMC;
    *(ushort4*)(Cs  + row * 136 + grp * 4) = *(const ushort4*)(src + 1152 + grp * 4);
    *(ushort4*)(Bsc + row * 136 + grp * 4) = *(const ushort4*)(src + 1024 + grp * 4);
  }
  __syncthreads();

  bf16x8 af[4];
#pragma unroll
  for (int ks = 0; ks < 4; ++ks)
    af[ks] = *(const bf16x8*)(Cs + (w * 16 + t) * 136 + ks * 32 + q * 8);

  f32x4 sacc[4];
#pragma unroll
  for (int j = 0; j < 4; ++j) sacc[j] = (f32x4){0.f, 0.f, 0.f, 0.f};
#pragma unroll
  for (int ks = 0; ks < 4; ++ks)
#pragma unroll
    for (int j = 0; j < 4; ++j) {
      bf16x8 bf = *(const bf16x8*)(Bsc + (j * 16 + t) * 136 + ks * 32 + q * 8);
      sacc[j] = __builtin_amdgcn_mfma_f32_16x16x32_bf16(af[ks], bf, sacc[j], 0, 0, 0);
    }

  for (int i = 0; i < 8; ++i) {
    int h = hb * 8 + i;
    __syncthreads();
    size_t pbase = ((size_t)(b * NCHUNKC + c) * NHEADSC + h) * 8192;
#pragma unroll
    for (int r = 0; r < 8; ++r) {
      int qq = tid + r * 256;
      int row = qq >> 5, grp = qq & 31;
      *(ushort4*)(Ps + row * 136 + grp * 4) =
          *(const ushort4*)(states + pbase + row * 128 + grp * 4);
    }
#pragma unroll
    for (int r = 0; r < 4; ++r) {
      int qq = tid + r * 256;
      int l = qq & 63, pg = qq >> 6;
      ushort4 v = *(const ushort4*)(xBC + (size_t)pos_of(b, c, l, dir) * CONV_DIMC + h * 64 + pg * 4);
      xhT[(pg * 4 + 0) * 72 + l] = v.x; xhT[(pg * 4 + 1) * 72 + l] = v.y;
      xhT[(pg * 4 + 2) * 72 + l] = v.z; xhT[(pg * 4 + 3) * 72 + l] = v.w;
    }
    if (tid < 64) {
      int gi = ((b * NCHUNKC + c) * NHEADSC + h) * 64 + tid;
      acumH[tid] = acum_g[gi]; dtH[tid] = dt_g[gi];
    }
    __syncthreads();

    f32x4 yacc[4];
#pragma unroll
    for (int j = 0; j < 4; ++j) yacc[j] = (f32x4){0.f, 0.f, 0.f, 0.f};
#pragma unroll
    for (int ks = 0; ks < 4; ++ks)
#pragma unroll
      for (int j = 0; j < 4; ++j) {
        bf16x8 bP = *(const bf16x8*)(Ps + (j * 16 + t) * 136 + ks * 32 + q * 8);
        yacc[j] = __builtin_amdgcn_mfma_f32_16x16x32_bf16(af[ks], bP, yacc[j], 0, 0, 0);
      }

    float Dh = D_skip[h];
    bfu* sc = Bsc;
#pragma unroll
    for (int j = 0; j < 4; ++j)
#pragma unroll
      for (int r = 0; r < 4; ++r) {
        int l = w * 16 + q * 4 + r, s = j * 16 + t;
        float v = 0.f;
        if (s <= l) v = sacc[j][r] * expf(acumH[l] - acumH[s]) * dtH[s];
        if (s == l) v += Dh;
        sc[l * 72 + s] = f2b(v);
      }

    f32x4 acc2[4];
    float dec[4];
#pragma unroll
    for (int r = 0; r < 4; ++r) dec[r] = expf(acumH[w * 16 + q * 4 + r]);
#pragma unroll
    for (int j = 0; j < 4; ++j)
#pragma unroll
      for (int r = 0; r < 4; ++r) acc2[j][r] = yacc[j][r] * dec[r];

#pragma unroll
    for (int ks = 0; ks < 2; ++ks) {
      bf16x8 asc = *(const bf16x8*)(sc + (w * 16 + t) * 72 + ks * 32 + q * 8);
#pragma unroll
      for (int j = 0; j < 4; ++j) {
        bf16x8 bx = *(const bf16x8*)(xhT + (j * 16 + t) * 72 + ks * 32 + q * 8);
        acc2[j] = __builtin_amdgcn_mfma_f32_16x16x32_bf16(asc, bx, acc2[j], 0, 0, 0);
      }
    }

#pragma unroll
    for (int j = 0; j < 4; ++j)
#pragma unroll
      for (int r = 0; r < 4; ++r) {
        int l = w * 16 + q * 4 + r, p = j * 16 + t;
        ybuf[(size_t)pos_of(b, c, l, dir) * D_INNERC + h * 64 + p] = f2b(acc2[j][r]);
      }
  }
}

// ---------------------------------------------------------------------------
// Gating (y *= silu(z)) + RMSNorm over 1024 + norm_w, in place on ybuf (bf16)
// ---------------------------------------------------------------------------
__global__ __launch_bounds__(256)
void norm_k(bfu* __restrict__ ybuf, const bfu* __restrict__ zx,
            const float* __restrict__ norm_w)
{
  int m = blockIdx.x, tid = threadIdx.x;
  float4 y = ld4(ybuf + (size_t)m * D_INNERC + tid * 4);
  float4 z = ld4(zx + (size_t)m * D_PROJC + tid * 4);
  float4 g;
  g.x = y.x * silu_(z.x); g.y = y.y * silu_(z.y);
  g.z = y.z * silu_(z.z); g.w = y.w * silu_(z.w);
  float ss = g.x * g.x + g.y * g.y + g.z * g.z + g.w * g.w;
#pragma unroll
  for (int off = 32; off >= 1; off >>= 1) ss += __shfl_xor(ss, off);
  __shared__ float red[4];
  int wid = tid >> 6;
  if ((tid & 63) == 0) red[wid] = ss;
  __syncthreads();
  float tot = red[0] + red[1] + red[2] + red[3];
  float scale = rsqrtf(tot * (1.f / 1024.f) + 1e-5f);
  float4 w = *(const float4*)(norm_w + tid * 4);
  g.x *= scale * w.x; g.y *= scale * w.y; g.z *= scale * w.z; g.w *= scale * w.w;
  st4(ybuf + (size_t)m * D_INNERC + tid * 4, g);
}

// ---------------------------------------------------------------------------
extern "C" void kernel_launch(void* const* d_in, const int* in_sizes, int n_in,
                              void* d_out, int out_size, void* d_ws, size_t ws_size,
                              hipStream_t stream)
{
  const float* x         = (const float*)d_in[0];
  const float* in_proj_w = (const float*)d_in[1];
  const float* conv_w    = (const float*)d_in[2];
  const float* conv_b    = (const float*)d_in[3];
  const float* dt_bias   = (const float*)d_in[4];
  const float* A_log     = (const float*)d_in[5];
  const float* D_skip    = (const float*)d_in[6];
  const float* norm_w    = (const float*)d_in[7];
  const float* ssm_out_w = (const float*)d_in[8];
  const float* fuse_w    = (const float*)d_in[9];
  const float* fuse_b    = (const float*)d_in[10];
  float* out = (float*)d_out;

  // workspace layout — ~225 MB
  bfu* zx     = (bfu*)d_ws;                          // 16384 x 2320 bf16
  bfu* xBC    = zx     + (size_t)M_ROWS * D_PROJC;   // 16384 x 1280 bf16
  bfu* states = xBC    + (size_t)M_ROWS * CONV_DIMC; // 33,554,432 bf16
  bfu* ybuf   = states + (size_t)33554432;           // 16384 x 1024 bf16
  float* acum = (float*)(ybuf + (size_t)M_ROWS * D_INNERC); // 262144 f32
  float* dtg  = acum + 262144;                       // 262144 f32
  bfu* ssmTb  = (bfu*)(dtg + 262144);                // 1024 x 512 bf16
  bfu* fuseA  = ssmTb + 524288;                      // 1024 x 512 bf16
  bfu* wcmb   = fuseA + 524288;                      // 2 x 512 x 1024 bf16
  // transient aliases inside the states region (dead before states_mfma_k):
  bfu* xb = states;                    // 16384 x 512 bf16
  bfu* wb = states + 8388608;          // 2432  x 512 bf16

  cvt_x_k<<<8192, 256, 0, stream>>>(x, xb);
  cvt_w_k<<<1216, 256, 0, stream>>>(in_proj_w, wb);
  transpose_k<<<2048, 256, 0, stream>>>(ssm_out_w, ssmTb);
  cvt_fuse_k<<<512, 256, 0, stream>>>(fuse_w, fuseA);

  // wcmb[dir][o][j] = sum_k fuse_w[o, dir*512+k] * ssm_out_w[k, j]
  // stacked M=1024 (m = dir*512+o), ldc=1024 -> lands exactly on wcmb layout
  mfma_nt<<<dim3(8, 8), 256, 0, stream>>>(
      fuseA, 512, ssmTb, 512, wcmb, 1024, 1024, 512, nullptr, 0);

  // in_proj: zx = x @ in_proj_w^T
  mfma_nt<<<dim3(19, 128), 256, 0, stream>>>(
      xb, 512, wb, 512, zx, D_PROJC, D_PROJC, 512, nullptr, 0);

  for (int dir = 0; dir < 2; ++dir) {
    conv_k<<<dim3(5, 2048), 256, 0, stream>>>(zx, conv_w, conv_b, xBC, dir);
    states_mfma_k<<<512, 256, 0, stream>>>(zx, xBC, dt_bias, A_log, acum, dtg, states, dir);
    scan_k<<<512, 256, 0, stream>>>(states, acum);
    y_mfma_k<<<512, 256, 0, stream>>>(xBC, states, acum, dtg, D_skip, ybuf, dir);
    norm_k<<<M_ROWS, 256, 0, stream>>>(ybuf, zx, norm_w);
    mfma_nt<<<dim3(4, 128), 256, 0, stream>>>(
        ybuf, 1024, wcmb + (size_t)dir * 524288, 1024, out, 512,
        512, 1024, dir == 0 ? fuse_b : nullptr, dir == 0 ? 1 : 2);
  }
}

// Round 7
// 529.061 us; speedup vs baseline: 4.2168x; 1.0808x over previous
//
#include <hip/hip_runtime.h>
#include <cstddef>

// Problem constants
#define B_SZ     2
#define L_SEQ    8192
#define D_INNERC 1024
#define NHEADSC  16
#define CHUNKC   64
#define NCHUNKC  128          // L_SEQ / CHUNK
#define CONV_DIMC 1280
#define D_PROJC  2320
#define M_ROWS   16384        // B_SZ * L_SEQ

typedef unsigned short bfu;   // raw bf16 bits

using bf16x8 = __attribute__((ext_vector_type(8))) short;
using f32x4  = __attribute__((ext_vector_type(4))) float;

__device__ __forceinline__ float silu_(float v) { return v / (1.f + expf(-v)); }

__device__ __forceinline__ float b2f(bfu u) {
  return __uint_as_float((unsigned)u << 16);
}
__device__ __forceinline__ bfu f2b(float f) {
  unsigned x = __float_as_uint(f);
  return (bfu)((x + 0x7fffu + ((x >> 16) & 1u)) >> 16);   // RNE
}

__device__ __forceinline__ float4 ld4(const float* p) { return *(const float4*)p; }
__device__ __forceinline__ float4 ld4(const bfu* p) {
  ushort4 u = *(const ushort4*)p;
  float4 f;
  f.x = b2f(u.x); f.y = b2f(u.y); f.z = b2f(u.z); f.w = b2f(u.w);
  return f;
}
__device__ __forceinline__ void st4(float* p, float4 v) { *(float4*)p = v; }
__device__ __forceinline__ void st4(bfu* p, float4 v) {
  ushort4 u;
  u.x = f2b(v.x); u.y = f2b(v.y); u.z = f2b(v.z); u.w = f2b(v.w);
  *(ushort4*)p = u;
}

__device__ __forceinline__ void gl_lds16(const bfu* g, bfu* l) {
  __builtin_amdgcn_global_load_lds(
      (const __attribute__((address_space(1))) unsigned int*)g,
      (__attribute__((address_space(3))) unsigned int*)l, 16, 0, 0);
}

__device__ __forceinline__ int pos_of(int b, int c, int l, int dir) {
  int t = c * CHUNKC + l;
  return dir ? (b * L_SEQ + (L_SEQ - 1) - t) : (b * L_SEQ + t);
}

// ---------------------------------------------------------------------------
// MFMA GEMM (NT): C[m][n] = sum_k A[m][k] * Bw[n][k].  A,B bf16, K-contig.
// 128x128 tile, BK=64 (K % 64 == 0), 256 thr = 4 waves 2x2, 4x4x(2 k-step)
// MFMAs of 16x16x32.  XCD swizzle (gridDim.y % 8 == 0): all N-tiles of an
// m-tile on one XCD.  LDS row = 64 elems, colgroup cg of 8 stored at
// cg ^ (r & 7) -> frag ds_read_b128 2-way aliased (free).
// Epilogue: LDS repack -> coalesced dwordx4 stores (and coalesced accum/bias).
// mode: 0 -> store bf16;  1 -> store f32 (+bias);  2 -> f32 +=
// ---------------------------------------------------------------------------
__global__ __launch_bounds__(256)
void mfma_nt(const bfu* __restrict__ A, int lda,
             const bfu* __restrict__ Bw, int ldb,
             void* __restrict__ Cv, int ldc,
             int N, int K, const float* __restrict__ bias, int mode)
{
  __shared__ bfu sh[16384];           // 32 KB: As | Bs, reused by epilogue
  bfu* As = sh;                       // 128 x 64
  bfu* Bs = sh + 8192;                // 128 x 64
  const int tid  = threadIdx.x;
  const int lane = tid & 63;
  const int wave = __builtin_amdgcn_readfirstlane(tid >> 6);
  const int wm = wave & 1, wn = wave >> 1;

  const int num_n = gridDim.x;
  const int flat  = blockIdx.y * num_n + blockIdx.x;
  const int xcd   = flat & 7;
  const int g     = flat >> 3;
  const int n0 = (g % num_n) * 128;
  const int m0 = ((g / num_n) * 8 + xcd) * 128;

  f32x4 acc[4][4];
#pragma unroll
  for (int i = 0; i < 4; ++i)
#pragma unroll
    for (int j = 0; j < 4; ++j)
      acc[i][j] = (f32x4){0.f, 0.f, 0.f, 0.f};

  const int ro   = lane >> 3;          // row within 8-row staging slice
  const int slot = lane & 7;           // stored colgroup slot

  for (int k0 = 0; k0 < K; k0 += 64) {
    __syncthreads();
    // each wave stages rows [wave*32, wave*32+32) of A and B, 8 rows/call
#pragma unroll
    for (int si = 0; si < 4; ++si) {
      int r = wave * 32 + si * 8 + ro;
      int cg = slot ^ (r & 7);
      gl_lds16(A  + (size_t)(m0 + r) * lda + k0 + cg * 8, As + (wave * 32 + si * 8) * 64);
      gl_lds16(Bw + (size_t)(n0 + r) * ldb + k0 + cg * 8, Bs + (wave * 32 + si * 8) * 64);
    }
    __syncthreads();

#pragma unroll
    for (int ks = 0; ks < 2; ++ks) {
      bf16x8 af[4], bfr[4];
#pragma unroll
      for (int i = 0; i < 4; ++i) {
        int ra = wm * 64 + i * 16 + (lane & 15);
        int ca = (ks * 4 + (lane >> 4)) ^ (ra & 7);
        af[i] = *(const bf16x8*)(As + ra * 64 + ca * 8);
        int rb = wn * 64 + i * 16 + (lane & 15);
        int cb = (ks * 4 + (lane >> 4)) ^ (rb & 7);
        bfr[i] = *(const bf16x8*)(Bs + rb * 64 + cb * 8);
      }
#pragma unroll
      for (int i = 0; i < 4; ++i)
#pragma unroll
        for (int j = 0; j < 4; ++j)
          acc[i][j] = __builtin_amdgcn_mfma_f32_16x16x32_bf16(af[i], bfr[j], acc[i][j], 0, 0, 0);
    }
  }

  // ---- epilogue: repack through LDS, coalesced dwordx4 stores ----
  // C/D layout: col = lane&15, row = (lane>>4)*4 + reg
  __syncthreads();
  if (mode == 0) {
    // whole 128x128 bf16 tile fits in 32 KB
#pragma unroll
    for (int i = 0; i < 4; ++i)
#pragma unroll
      for (int j = 0; j < 4; ++j)
#pragma unroll
        for (int r = 0; r < 4; ++r) {
          int ml = wm * 64 + i * 16 + (lane >> 4) * 4 + r;
          int nl = wn * 64 + j * 16 + (lane & 15);
          sh[ml * 128 + nl] = f2b(acc[i][j][r]);
        }
    __syncthreads();
    bfu* Cb = (bfu*)Cv;
#pragma unroll
    for (int rr = 0; rr < 8; ++rr) {
      int idx = rr * 256 + tid;            // 8-elem group id, 0..2047
      int row = idx >> 4, co = (idx & 15) * 8;
      if (n0 + co < N) {                   // N is 8-aligned
        *(ulonglong2*)(Cb + (size_t)(m0 + row) * ldc + n0 + co) =
            *(const ulonglong2*)(sh + row * 128 + co);
      }
    }
  } else {
    float* Cf = (float*)Cv;
    float* shf = (float*)sh;               // 64 rows x 128 f32 per pass
#pragma unroll
    for (int p = 0; p < 2; ++p) {
      if (wm == p) {
#pragma unroll
        for (int i = 0; i < 4; ++i)
#pragma unroll
          for (int j = 0; j < 4; ++j)
#pragma unroll
            for (int r = 0; r < 4; ++r) {
              int ml = i * 16 + (lane >> 4) * 4 + r;   // 0..63
              int nl = wn * 64 + j * 16 + (lane & 15);
              shf[ml * 128 + nl] = acc[i][j][r];
            }
      }
      __syncthreads();
#pragma unroll
      for (int rr = 0; rr < 8; ++rr) {
        int idx = rr * 256 + tid;          // float4 group id, 0..2047
        int row = idx >> 5, co = (idx & 31) * 4;
        int n = n0 + co;
        if (n < N) {
          float4 v = *(float4*)(shf + row * 128 + co);
          float* cp = Cf + (size_t)(m0 + p * 64 + row) * ldc + n;
          if (mode == 2) {
            float4 o = *(float4*)cp;
            v.x += o.x; v.y += o.y; v.z += o.z; v.w += o.w;
          } else if (bias) {
            v.x += bias[n]; v.y += bias[n + 1]; v.z += bias[n + 2]; v.w += bias[n + 3];
          }
          *(float4*)cp = v;
        }
      }
      __syncthreads();
    }
  }
}

// ---------------------------------------------------------------------------
// setup converts (all fp32 -> bf16)
// ---------------------------------------------------------------------------
__global__ __launch_bounds__(256)
void cvt_x_k(const float* __restrict__ in, bfu* __restrict__ out)
{
  int q = blockIdx.x * 256 + threadIdx.x;
  st4(out + (size_t)q * 4, ld4(in + (size_t)q * 4));
}

__global__ __launch_bounds__(256)
void cvt_w_k(const float* __restrict__ in, bfu* __restrict__ out)
{
  int q = blockIdx.x * 256 + threadIdx.x;
  int row = q >> 7, c4 = (q & 127) << 2;
  float4 v = {0.f, 0.f, 0.f, 0.f};
  if (row < D_PROJC) v = ld4(in + (size_t)row * 512 + c4);
  st4(out + (size_t)row * 512 + c4, v);
}

// ssm_out_w (512 x 1024 f32) -> ssmTb (1024 x 512 bf16)
__global__ __launch_bounds__(256)
void transpose_k(const float* __restrict__ in, bfu* __restrict__ out)
{
  int idx = blockIdx.x * 256 + threadIdx.x;   // 0 .. 524287
  int j = idx >> 9, k = idx & 511;
  out[idx] = f2b(in[k * 1024 + j]);
}

// fuse_w (512 x 1024 f32) -> fuseA (1024 x 512 bf16), row m = dir*512 + o
__global__ __launch_bounds__(256)
void cvt_fuse_k(const float* __restrict__ in, bfu* __restrict__ out)
{
  int q = blockIdx.x * 256 + threadIdx.x;     // 0 .. 131071 (4-elem groups)
  int m = q >> 7, kg = (q & 127) << 2;
  float4 v = ld4(in + (size_t)(m & 511) * 1024 + (m >> 9) * 512 + kg);
  st4(out + (size_t)m * 512 + kg, v);
}

// ---------------------------------------------------------------------------
// Depthwise conv + bias + SiLU, 8 outputs per thread (taps staged in regs).
// ---------------------------------------------------------------------------
__global__ __launch_bounds__(256)
void conv_k(const bfu* __restrict__ zx, const float* __restrict__ conv_w,
            const float* __restrict__ conv_b, bfu* __restrict__ xBC, int dir)
{
  int ch = blockIdx.x * 256 + threadIdx.x;   // 0..1279
  int m0 = blockIdx.y * 8;                   // global row base
  int b  = m0 >> 13, tb = m0 & (L_SEQ - 1);
  float w0 = conv_w[ch * 4 + 0], w1 = conv_w[ch * 4 + 1];
  float w2 = conv_w[ch * 4 + 2], w3 = conv_w[ch * 4 + 3];
  float cb = conv_b[ch];
  const bfu* src = zx + 1024 + ch;
  const int shift = dir ? 0 : 3;

  float v[11];
#pragma unroll
  for (int i = 0; i < 11; ++i) {
    int tt = tb + i - shift;
    v[i] = (tt >= 0 && tt < L_SEQ)
         ? b2f(src[(size_t)(b * L_SEQ + tt) * D_PROJC]) : 0.f;
  }
#pragma unroll
  for (int j = 0; j < 8; ++j) {
    float acc = cb;
    if (dir == 0) {
      acc += w0 * v[j] + w1 * v[j + 1] + w2 * v[j + 2] + w3 * v[j + 3];
    } else {
      acc += w0 * v[j + 3] + w1 * v[j + 2] + w2 * v[j + 1] + w3 * v[j];
    }
    xBC[(size_t)(m0 + j) * CONV_DIMC + ch] = f2b(silu_(acc));
  }
}

// ---------------------------------------------------------------------------
// MFMA states: per (b,c) block, 8 heads/block (grid 512/dir).
// ---------------------------------------------------------------------------
__global__ __launch_bounds__(256)
void states_mfma_k(const bfu* __restrict__ zx, const bfu* __restrict__ xBC,
                   const float* __restrict__ dt_bias, const float* __restrict__ A_log,
                   float* __restrict__ acum_g, float* __restrict__ dt_g,
                   bfu* __restrict__ states, int dir)
{
  __shared__ bfu BT[128 * 72];     // [n][l]
  __shared__ bfu xsT[64 * 72];     // [p][l]
  __shared__ float scaleS[8 * 64];

  int bid = blockIdx.x;
  int hb = bid >> 8;
  int c = bid & 127, b = (bid >> 7) & 1;
  int tid = threadIdx.x, lane = tid & 63;
  int w = tid >> 6, q = lane >> 4, t = lane & 15;

#pragma unroll
  for (int rr = 0; rr < 2; ++rr) {
    int i = w + rr * 4;
    int h = hb * 8 + i;
    int l = lane;
    int pos = pos_of(b, c, l, dir);
    float dtr = b2f(zx[(size_t)pos * D_PROJC + 2304 + h]) + dt_bias[h];
    float dt = (dtr > 20.f) ? dtr : log1pf(expf(dtr));
    float a = -expf(A_log[h]) * dt;
#pragma unroll
    for (int off = 1; off < 64; off <<= 1) {
      float v = __shfl_up(a, off);
      if (l >= off) a += v;
    }
    float alast = __shfl(a, 63);
    int gi = ((b * NCHUNKC + c) * NHEADSC + h) * 64 + l;
    acum_g[gi] = a; dt_g[gi] = dt;
    scaleS[i * 64 + l] = dt * expf(alast - a);
  }

#pragma unroll
  for (int r = 0; r < 8; ++r) {
    int qq = tid + r * 256;
    int l = qq & 63, ng = qq >> 6;
    ushort4 v = *(const ushort4*)(xBC + (size_t)pos_of(b, c, l, dir) * CONV_DIMC + 1024 + ng * 4);
    BT[(ng * 4 + 0) * 72 + l] = v.x; BT[(ng * 4 + 1) * 72 + l] = v.y;
    BT[(ng * 4 + 2) * 72 + l] = v.z; BT[(ng * 4 + 3) * 72 + l] = v.w;
  }
  __syncthreads();

  for (int i = 0; i < 8; ++i) {
    int h = hb * 8 + i;
#pragma unroll
    for (int r = 0; r < 4; ++r) {
      int qq = tid + r * 256;
      int l = qq & 63, pg = qq >> 6;
      float s = scaleS[i * 64 + l];
      ushort4 v = *(const ushort4*)(xBC + (size_t)pos_of(b, c, l, dir) * CONV_DIMC + h * 64 + pg * 4);
      xsT[(pg * 4 + 0) * 72 + l] = f2b(b2f(v.x) * s);
      xsT[(pg * 4 + 1) * 72 + l] = f2b(b2f(v.y) * s);
      xsT[(pg * 4 + 2) * 72 + l] = f2b(b2f(v.z) * s);
      xsT[(pg * 4 + 3) * 72 + l] = f2b(b2f(v.w) * s);
    }
    __syncthreads();

    bf16x8 axs[2];
#pragma unroll
    for (int ks = 0; ks < 2; ++ks)
      axs[ks] = *(const bf16x8*)(xsT + (w * 16 + t) * 72 + ks * 32 + q * 8);

    f32x4 acc[8];
#pragma unroll
    for (int j = 0; j < 8; ++j) acc[j] = (f32x4){0.f, 0.f, 0.f, 0.f};
#pragma unroll
    for (int ks = 0; ks < 2; ++ks)
#pragma unroll
      for (int j = 0; j < 8; ++j) {
        bf16x8 bB = *(const bf16x8*)(BT + (j * 16 + t) * 72 + ks * 32 + q * 8);
        acc[j] = __builtin_amdgcn_mfma_f32_16x16x32_bf16(axs[ks], bB, acc[j], 0, 0, 0);
      }

    size_t base = ((size_t)(b * NCHUNKC + c) * NHEADSC + h) * 8192;
#pragma unroll
    for (int j = 0; j < 8; ++j)
#pragma unroll
      for (int r = 0; r < 4; ++r) {
        int p = w * 16 + q * 4 + r, n = j * 16 + t;
        states[base + p * 128 + n] = f2b(acc[j][r]);
      }
    __syncthreads();
  }
}

// ---------------------------------------------------------------------------
// Inter-chunk scan with explicit next-chunk prefetch.  512 blocks: (b,h,eb)
// ---------------------------------------------------------------------------
__global__ __launch_bounds__(256)
void scan_k(bfu* __restrict__ states, const float* __restrict__ acum_g)
{
  int bid = blockIdx.x;
  int eb = bid & 15, h = (bid >> 4) & 15, b = bid >> 8;
  int e = eb * 512 + threadIdx.x * 2;
  bfu* p0 = states + ((size_t)(b * NCHUNKC) * NHEADSC + h) * 8192 + e;
  const float* ac = acum_g + ((b * NCHUNKC) * NHEADSC + h) * 64 + 63;
  const size_t cstride = (size_t)NHEADSC * 8192;
  const int astride = NHEADSC * 64;

  float pre0 = 0.f, pre1 = 0.f;
  uint raw = *(const uint*)p0;
  float dcur = expf(ac[0]);
  for (int c = 0; c < NCHUNKC; ++c) {
    uint raw_next = 0; float dnext = 0.f;
    if (c < NCHUNKC - 1) {
      raw_next = *(const uint*)(p0 + (c + 1) * cstride);
      dnext = expf(ac[(c + 1) * astride]);
    }
    float v0 = b2f((bfu)(raw & 0xffff));
    float v1 = b2f((bfu)(raw >> 16));
    uint packed = (uint)f2b(pre0) | ((uint)f2b(pre1) << 16);
    *(uint*)(p0 + c * cstride) = packed;
    pre0 = v0 + dcur * pre0;
    pre1 = v1 + dcur * pre1;
    raw = raw_next; dcur = dnext;
  }
}

// ---------------------------------------------------------------------------
// MFMA Y: per (b,c) block, 8 heads/block (grid 512/dir).
// ---------------------------------------------------------------------------
__global__ __launch_bounds__(256)
void y_mfma_k(const bfu* __restrict__ xBC, const bfu* __restrict__ states,
              const float* __restrict__ acum_g, const float* __restrict__ dt_g,
              const float* __restrict__ D_skip, bfu* __restrict__ ybuf, int dir)
{
  __shared__ bfu smem[30976];
  bfu* Cs  = smem;                      // 64 x 136
  bfu* Bsc = smem + 8704;               // 64 x 136 (B tile; sc overlays)
  bfu* Ps  = smem + 17408;              // 64 x 136
  bfu* xhT = smem + 26112;              // 64 x 72
  float* acumH = (float*)(smem + 30720);
  float* dtH   = acumH + 64;

  int bid = blockIdx.x;
  int hb = bid >> 8;
  int c = bid & 127, b = (bid >> 7) & 1;
  int tid = threadIdx.x, lane = tid & 63;
  int w = tid >> 6, q = lane >> 4, t = lane & 15;

#pragma unroll
  for (int r = 0; r < 8; ++r) {
    int qq = tid + r * 256;
    int row = qq >> 5, grp = qq & 31;
    const bfu* src = xBC + (size_t)pos_of(b, c, row, dir) * CONV_DIMC;
    *(ushort4*)(Cs  + row * 136 + grp * 4) = *(const ushort4*)(src + 1152 + grp * 4);
    *(ushort4*)(Bsc + row * 136 + grp * 4) = *(const ushort4*)(src + 1024 + grp * 4);
  }
  __syncthreads();

  bf16x8 af[4];
#pragma unroll
  for (int ks = 0; ks < 4; ++ks)
    af[ks] = *(const bf16x8*)(Cs + (w * 16 + t) * 136 + ks * 32 + q * 8);

  f32x4 sacc[4];
#pragma unroll
  for (int j = 0; j < 4; ++j) sacc[j] = (f32x4){0.f, 0.f, 0.f, 0.f};
#pragma unroll
  for (int ks = 0; ks < 4; ++ks)
#pragma unroll
    for (int j = 0; j < 4; ++j) {
      bf16x8 bf = *(const bf16x8*)(Bsc + (j * 16 + t) * 136 + ks * 32 + q * 8);
      sacc[j] = __builtin_amdgcn_mfma_f32_16x16x32_bf16(af[ks], bf, sacc[j], 0, 0, 0);
    }

  for (int i = 0; i < 8; ++i) {
    int h = hb * 8 + i;
    __syncthreads();
    size_t pbase = ((size_t)(b * NCHUNKC + c) * NHEADSC + h) * 8192;
#pragma unroll
    for (int r = 0; r < 8; ++r) {
      int qq = tid + r * 256;
      int row = qq >> 5, grp = qq & 31;
      *(ushort4*)(Ps + row * 136 + grp * 4) =
          *(const ushort4*)(states + pbase + row * 128 + grp * 4);
    }
#pragma unroll
    for (int r = 0; r < 4; ++r) {
      int qq = tid + r * 256;
      int l = qq & 63, pg = qq >> 6;
      ushort4 v = *(const ushort4*)(xBC + (size_t)pos_of(b, c, l, dir) * CONV_DIMC + h * 64 + pg * 4);
      xhT[(pg * 4 + 0) * 72 + l] = v.x; xhT[(pg * 4 + 1) * 72 + l] = v.y;
      xhT[(pg * 4 + 2) * 72 + l] = v.z; xhT[(pg * 4 + 3) * 72 + l] = v.w;
    }
    if (tid < 64) {
      int gi = ((b * NCHUNKC + c) * NHEADSC + h) * 64 + tid;
      acumH[tid] = acum_g[gi]; dtH[tid] = dt_g[gi];
    }
    __syncthreads();

    f32x4 yacc[4];
#pragma unroll
    for (int j = 0; j < 4; ++j) yacc[j] = (f32x4){0.f, 0.f, 0.f, 0.f};
#pragma unroll
    for (int ks = 0; ks < 4; ++ks)
#pragma unroll
      for (int j = 0; j < 4; ++j) {
        bf16x8 bP = *(const bf16x8*)(Ps + (j * 16 + t) * 136 + ks * 32 + q * 8);
        yacc[j] = __builtin_amdgcn_mfma_f32_16x16x32_bf16(af[ks], bP, yacc[j], 0, 0, 0);
      }

    float Dh = D_skip[h];
    bfu* sc = Bsc;
#pragma unroll
    for (int j = 0; j < 4; ++j)
#pragma unroll
      for (int r = 0; r < 4; ++r) {
        int l = w * 16 + q * 4 + r, s = j * 16 + t;
        float v = 0.f;
        if (s <= l) v = sacc[j][r] * expf(acumH[l] - acumH[s]) * dtH[s];
        if (s == l) v += Dh;
        sc[l * 72 + s] = f2b(v);
      }

    f32x4 acc2[4];
    float dec[4];
#pragma unroll
    for (int r = 0; r < 4; ++r) dec[r] = expf(acumH[w * 16 + q * 4 + r]);
#pragma unroll
    for (int j = 0; j < 4; ++j)
#pragma unroll
      for (int r = 0; r < 4; ++r) acc2[j][r] = yacc[j][r] * dec[r];

#pragma unroll
    for (int ks = 0; ks < 2; ++ks) {
      bf16x8 asc = *(const bf16x8*)(sc + (w * 16 + t) * 72 + ks * 32 + q * 8);
#pragma unroll
      for (int j = 0; j < 4; ++j) {
        bf16x8 bx = *(const bf16x8*)(xhT + (j * 16 + t) * 72 + ks * 32 + q * 8);
        acc2[j] = __builtin_amdgcn_mfma_f32_16x16x32_bf16(asc, bx, acc2[j], 0, 0, 0);
      }
    }

#pragma unroll
    for (int j = 0; j < 4; ++j)
#pragma unroll
      for (int r = 0; r < 4; ++r) {
        int l = w * 16 + q * 4 + r, p = j * 16 + t;
        ybuf[(size_t)pos_of(b, c, l, dir) * D_INNERC + h * 64 + p] = f2b(acc2[j][r]);
      }
  }
}

// ---------------------------------------------------------------------------
// Gating (y *= silu(z)) + RMSNorm over 1024 + norm_w, in place on ybuf (bf16)
// ---------------------------------------------------------------------------
__global__ __launch_bounds__(256)
void norm_k(bfu* __restrict__ ybuf, const bfu* __restrict__ zx,
            const float* __restrict__ norm_w)
{
  int m = blockIdx.x, tid = threadIdx.x;
  float4 y = ld4(ybuf + (size_t)m * D_INNERC + tid * 4);
  float4 z = ld4(zx + (size_t)m * D_PROJC + tid * 4);
  float4 g;
  g.x = y.x * silu_(z.x); g.y = y.y * silu_(z.y);
  g.z = y.z * silu_(z.z); g.w = y.w * silu_(z.w);
  float ss = g.x * g.x + g.y * g.y + g.z * g.z + g.w * g.w;
#pragma unroll
  for (int off = 32; off >= 1; off >>= 1) ss += __shfl_xor(ss, off);
  __shared__ float red[4];
  int wid = tid >> 6;
  if ((tid & 63) == 0) red[wid] = ss;
  __syncthreads();
  float tot = red[0] + red[1] + red[2] + red[3];
  float scale = rsqrtf(tot * (1.f / 1024.f) + 1e-5f);
  float4 w = *(const float4*)(norm_w + tid * 4);
  g.x *= scale * w.x; g.y *= scale * w.y; g.z *= scale * w.z; g.w *= scale * w.w;
  st4(ybuf + (size_t)m * D_INNERC + tid * 4, g);
}

// ---------------------------------------------------------------------------
extern "C" void kernel_launch(void* const* d_in, const int* in_sizes, int n_in,
                              void* d_out, int out_size, void* d_ws, size_t ws_size,
                              hipStream_t stream)
{
  const float* x         = (const float*)d_in[0];
  const float* in_proj_w = (const float*)d_in[1];
  const float* conv_w    = (const float*)d_in[2];
  const float* conv_b    = (const float*)d_in[3];
  const float* dt_bias   = (const float*)d_in[4];
  const float* A_log     = (const float*)d_in[5];
  const float* D_skip    = (const float*)d_in[6];
  const float* norm_w    = (const float*)d_in[7];
  const float* ssm_out_w = (const float*)d_in[8];
  const float* fuse_w    = (const float*)d_in[9];
  const float* fuse_b    = (const float*)d_in[10];
  float* out = (float*)d_out;

  // workspace layout — ~225 MB
  bfu* zx     = (bfu*)d_ws;                          // 16384 x 2320 bf16
  bfu* xBC    = zx     + (size_t)M_ROWS * D_PROJC;   // 16384 x 1280 bf16
  bfu* states = xBC    + (size_t)M_ROWS * CONV_DIMC; // 33,554,432 bf16
  bfu* ybuf   = states + (size_t)33554432;           // 16384 x 1024 bf16
  float* acum = (float*)(ybuf + (size_t)M_ROWS * D_INNERC); // 262144 f32
  float* dtg  = acum + 262144;                       // 262144 f32
  bfu* ssmTb  = (bfu*)(dtg + 262144);                // 1024 x 512 bf16
  bfu* fuseA  = ssmTb + 524288;                      // 1024 x 512 bf16
  bfu* wcmb   = fuseA + 524288;                      // 2 x 512 x 1024 bf16
  // transient aliases inside the states region (dead before states_mfma_k):
  bfu* xb = states;                    // 16384 x 512 bf16
  bfu* wb = states + 8388608;          // 2432  x 512 bf16

  cvt_x_k<<<8192, 256, 0, stream>>>(x, xb);
  cvt_w_k<<<1216, 256, 0, stream>>>(in_proj_w, wb);
  transpose_k<<<2048, 256, 0, stream>>>(ssm_out_w, ssmTb);
  cvt_fuse_k<<<512, 256, 0, stream>>>(fuse_w, fuseA);

  // wcmb[dir][o][j] = sum_k fuse_w[o, dir*512+k] * ssm_out_w[k, j]
  mfma_nt<<<dim3(8, 8), 256, 0, stream>>>(
      fuseA, 512, ssmTb, 512, wcmb, 1024, 1024, 512, nullptr, 0);

  // in_proj: zx = x @ in_proj_w^T
  mfma_nt<<<dim3(19, 128), 256, 0, stream>>>(
      xb, 512, wb, 512, zx, D_PROJC, D_PROJC, 512, nullptr, 0);

  for (int dir = 0; dir < 2; ++dir) {
    conv_k<<<dim3(5, 2048), 256, 0, stream>>>(zx, conv_w, conv_b, xBC, dir);
    states_mfma_k<<<512, 256, 0, stream>>>(zx, xBC, dt_bias, A_log, acum, dtg, states, dir);
    scan_k<<<512, 256, 0, stream>>>(states, acum);
    y_mfma_k<<<512, 256, 0, stream>>>(xBC, states, acum, dtg, D_skip, ybuf, dir);
    norm_k<<<M_ROWS, 256, 0, stream>>>(ybuf, zx, norm_w);
    mfma_nt<<<dim3(4, 128), 256, 0, stream>>>(
        ybuf, 1024, wcmb + (size_t)dir * 524288, 1024, out, 512,
        512, 1024, dir == 0 ? fuse_b : nullptr, dir == 0 ? 1 : 2);
  }
}